// Round 4
// baseline (488.510 us; speedup 1.0000x reference)
//
#include <hip/hip_runtime.h>
#include <math.h>

typedef unsigned short u16;
typedef __attribute__((ext_vector_type(8))) short bf16x8;
typedef __attribute__((ext_vector_type(4))) float f32x4;

#define DHID 1024

__device__ __forceinline__ u16 f2bf(float f) {
  union { float f; unsigned u; } v; v.f = f;
  unsigned u = v.u;
  u = (u + 0x7fffu + ((u >> 16) & 1u)) >> 16;
  return (u16)u;
}
__device__ __forceinline__ float bf2f(u16 h) {
  union { unsigned u; float f; } v; v.u = ((unsigned)h) << 16;
  return v.f;
}
__device__ __forceinline__ float wred(float v) {
  #pragma unroll
  for (int m = 32; m > 0; m >>= 1) v += __shfl_xor(v, m, 64);
  return v;
}
// ---- fast math: v_rcp_f32 / v_exp_f32 / v_log_f32 based ----
__device__ __forceinline__ float frcp(float x) { return __builtin_amdgcn_rcpf(x); }
__device__ __forceinline__ float ftanh(float x) {
  x = fminf(fmaxf(x, -15.f), 15.f);            // tanh(15) = 1 - 1e-13; avoids inf*0
  float t = __expf(2.f * x);
  return (t - 1.f) * frcp(t + 1.f);
}
__device__ __forceinline__ float fatanh(float x) {   // includes EPS clamp of reference
  x = fminf(fmaxf(x, -1.0f + 1e-5f), 1.0f - 1e-5f);
  return 0.5f * __logf((1.f + x) * frcp(1.f - x));
}
__device__ __forceinline__ float fsig(float x) {     // 1/(1+e^-x)
  return frcp(1.f + __expf(-x));
}

// ---------- fused weight convert+transpose for all 6: dst[n][k] = bf16(src[k][n]) ----------
struct W6 { const float* s[6]; u16* d[6]; };
__global__ __launch_bounds__(256) void wconv_all(W6 p) {
  const float* __restrict__ src = p.s[blockIdx.z];
  u16* __restrict__ dst = p.d[blockIdx.z];
  __shared__ float t[32][33];
  int bx = blockIdx.x * 32, by = blockIdx.y * 32;
  int tx = threadIdx.x, ty = threadIdx.y;
  #pragma unroll
  for (int r = 0; r < 32; r += 8)
    t[ty + r][tx] = src[(size_t)(by + ty + r) * DHID + bx + tx];
  __syncthreads();
  #pragma unroll
  for (int r = 0; r < 32; r += 8)
    dst[(size_t)(bx + ty + r) * DHID + by + tx] = f2bf(t[tx][ty + r]);
}

// ---------- prep: row norms + bf16 casts ----------
__global__ __launch_bounds__(256) void prep(const float* __restrict__ x, const float* __restrict__ h,
    u16* __restrict__ xb, u16* __restrict__ hb, float* __restrict__ nx, float* __restrict__ nh, int B) {
  int row = blockIdx.x * 4 + (threadIdx.x >> 6);
  if (row >= B) return;
  int lane = threadIdx.x & 63;
  size_t base = (size_t)row * DHID;
  const float4* xr = (const float4*)(x + base);
  const float4* hr = (const float4*)(h + base);
  ushort4* xo = (ushort4*)(xb + base);
  ushort4* ho = (ushort4*)(hb + base);
  float sx = 0.f, sh = 0.f;
  #pragma unroll
  for (int j = 0; j < 4; ++j) {
    int idx = j * 64 + lane;
    float4 a = xr[idx], b = hr[idx];
    sx += a.x*a.x + a.y*a.y + a.z*a.z + a.w*a.w;
    sh += b.x*b.x + b.y*b.y + b.z*b.z + b.w*b.w;
    xo[idx] = make_ushort4(f2bf(a.x), f2bf(a.y), f2bf(a.z), f2bf(a.w));
    ho[idx] = make_ushort4(f2bf(b.x), f2bf(b.y), f2bf(b.z), f2bf(b.w));
  }
  sx = wred(sx); sh = wred(sh);
  if (lane == 0) { nx[row] = sqrtf(sx); nh[row] = sqrtf(sh); }
}

// ---------- async global->LDS staging helper (width 16B) ----------
__device__ __forceinline__ void gll16(const void* g, void* l) {
  __builtin_amdgcn_global_load_lds((const __attribute__((address_space(1))) unsigned int*)g,
                                   (__attribute__((address_space(3))) unsigned int*)l, 16, 0, 0);
}

// ---------- bf16 MFMA GEMM (m97 structure): C[M][N] = A[M][K] @ Bt[N][K]^T ----------
__global__ __launch_bounds__(256) void gemm_bf16(const u16* __restrict__ A,
    const u16* __restrict__ Bt, u16* __restrict__ C, int M, int N, int K) {
  // linear LDS (global_load_lds writes base + lane*16B; no padding allowed)
  __shared__ __align__(16) u16 As[128 * 64];
  __shared__ __align__(16) u16 Bs[128 * 64];
  const int tid = threadIdx.x;
  const int lane = tid & 63;
  const int wid = tid >> 6;
  const int wr = (wid >> 1) * 64;
  const int wc = (wid & 1) * 64;
  const int l15 = lane & 15;
  const int koff = (lane >> 4) * 8;
  // staging geometry: wave w, issue i covers tile rows (i*4+w)*8 .. +8
  const int srow = lane >> 3;          // 0..7 within 8-row chunk
  const int scol = (lane & 7) * 8;     // u16 col, 8 elems = 16B
  const size_t abase = (size_t)(blockIdx.x * 128) * K;
  const size_t bbase = (size_t)(blockIdx.y * 128) * K;
  f32x4 acc[4][4] = {};
  for (int k0 = 0; k0 < K; k0 += 64) {
    __syncthreads();   // previous tile fully consumed
    #pragma unroll
    for (int i = 0; i < 4; ++i) {
      int rb = (i * 4 + wid) * 8;
      gll16(A  + abase + (size_t)(rb + srow) * K + k0 + scol, &As[rb * 64]);
      gll16(Bt + bbase + (size_t)(rb + srow) * K + k0 + scol, &Bs[rb * 64]);
    }
    __syncthreads();   // compiler drains vmcnt(0) before barrier
    #pragma unroll
    for (int ks = 0; ks < 64; ks += 32) {
      bf16x8 af[4], bg[4];
      #pragma unroll
      for (int m = 0; m < 4; ++m) af[m] = *(const bf16x8*)&As[(wr + m*16 + l15) * 64 + ks + koff];
      #pragma unroll
      for (int n = 0; n < 4; ++n) bg[n] = *(const bf16x8*)&Bs[(wc + n*16 + l15) * 64 + ks + koff];
      #pragma unroll
      for (int m = 0; m < 4; ++m)
        #pragma unroll
        for (int n = 0; n < 4; ++n)
          acc[m][n] = __builtin_amdgcn_mfma_f32_16x16x32_bf16(af[m], bg[n], acc[m][n], 0, 0, 0);
    }
  }
  const int r4 = (lane >> 4) * 4;
  #pragma unroll
  for (int m = 0; m < 4; ++m)
    #pragma unroll
    for (int n = 0; n < 4; ++n) {
      size_t col = (size_t)blockIdx.y * 128 + wc + n * 16 + l15;
      #pragma unroll
      for (int j = 0; j < 4; ++j) {
        size_t row = (size_t)blockIdx.x * 128 + wr + m * 16 + r4 + j;
        C[row * N + col] = f2bf(acc[m][n][j]);
      }
    }
}

// ---------- row helpers ----------
__device__ __forceinline__ void load_bf16_row(const u16* p, int lane, float v[16]) {
  #pragma unroll
  for (int j = 0; j < 4; ++j) {
    int idx = j * 64 + lane;
    ushort4 a = ((const ushort4*)p)[idx];
    v[4*j+0] = bf2f(a.x); v[4*j+1] = bf2f(a.y); v[4*j+2] = bf2f(a.z); v[4*j+3] = bf2f(a.w);
  }
}
__device__ __forceinline__ void load_f32_row(const float* p, int lane, float v[16]) {
  #pragma unroll
  for (int j = 0; j < 4; ++j) {
    int idx = j * 64 + lane;
    float4 a = ((const float4*)p)[idx];
    v[4*j+0] = a.x; v[4*j+1] = a.y; v[4*j+2] = a.z; v[4*j+3] = a.w;
  }
}

struct RowCtx {
  float scale_h, hnc, ath, scale_x, xn, atx;
};

__device__ __forceinline__ RowCtx make_ctx(float n_h, float n_x) {
  RowCtx c;
  c.scale_h = (n_h > 0.9999f) ? 0.9999f * frcp(n_h + 1e-10f) : 1.0f;
  float hn = n_h * c.scale_h;
  c.hnc = fmaxf(hn, 1e-10f);
  c.ath = fatanh(hn);
  float nxc = fmaxf(n_x, 1e-10f);
  c.scale_x = ftanh(nxc) * frcp(nxc);
  c.xn = fmaxf(n_x * c.scale_x, 1e-10f);
  c.atx = fatanh(c.xn);
  return c;
}

// one_transform + log0 + sigmoid for one gate (gh = state_raw@W, gx = inputs_raw@U)
__device__ __forceinline__ void gate_sig(const float gh[16], const float gx[16], const float bb[16],
                                         const RowCtx& c, float out[16], float sv[16]) {
  float sh = 0.f, sx = 0.f, dxy = 0.f;
  #pragma unroll
  for (int j = 0; j < 16; ++j) { sh += gh[j]*gh[j]; sx += gx[j]*gx[j]; dxy += gh[j]*gx[j]; }
  sh = wred(sh); sx = wred(sx); dxy = wred(dxy);
  float mhn = fmaxf(c.scale_h * sqrtf(sh), 1e-10f);
  float th  = ftanh(mhn * frcp(c.hnc) * c.ath);
  float ca  = th * c.scale_h * frcp(mhn);      // u[j] = ca*gh[j]
  float mxn = fmaxf(c.scale_x * sqrtf(sx), 1e-10f);
  float tx  = ftanh(mxn * frcp(c.xn) * c.atx);
  float cb  = tx * c.scale_x * frcp(mxn);      // v[j] = cb*gx[j]
  float uv = ca * cb * dxy;
  float u2 = th * th, v2 = tx * tx;
  float rden = frcp(1.f + 2.f*uv + u2*v2 + 1e-10f);
  float c1 = (1.f + 2.f*uv + v2) * rden * ca;
  float c2 = (1.f - u2) * rden * cb;
  float uvb = 0.f, u2s = 0.f, v2b = 0.f;
  #pragma unroll
  for (int j = 0; j < 16; ++j) {
    sv[j] = c1 * gh[j] + c2 * gx[j];
    uvb += sv[j] * bb[j]; u2s += sv[j] * sv[j]; v2b += bb[j] * bb[j];
  }
  uvb = wred(uvb); u2s = wred(u2s); v2b = wred(v2b);
  float rden2 = frcp(1.f + 2.f*uvb + u2s*v2b + 1e-10f);
  float d1 = (1.f + 2.f*uvb + v2b) * rden2, d2 = (1.f - u2s) * rden2;
  float s3 = 0.f;
  #pragma unroll
  for (int j = 0; j < 16; ++j) { sv[j] = d1 * sv[j] + d2 * bb[j]; s3 += sv[j]*sv[j]; }
  s3 = wred(s3);
  float ns = sqrtf(s3);
  float ps = (ns > 0.99999f) ? 0.99999f * frcp(ns + 1e-10f) : 1.0f;
  float nres = fmaxf(ns * ps, 1e-10f);
  float g = fatanh(nres) * frcp(nres) * ps;
  #pragma unroll
  for (int j = 0; j < 16; ++j) out[j] = fsig(g * sv[j]);
}

// ---------- gates: z (-> d_out), r, r_point_h (-> bf16), rn ----------
__global__ __launch_bounds__(256) void gates_k(
    const u16* __restrict__ Gzh, const u16* __restrict__ Gzx,
    const u16* __restrict__ Grh, const u16* __restrict__ Grx,
    const float* __restrict__ state, const float* __restrict__ bz, const float* __restrict__ br,
    const float* __restrict__ nxA, const float* __restrict__ nhA,
    float* __restrict__ zout, u16* __restrict__ rphb, float* __restrict__ rnA, int B) {
  int row = blockIdx.x * 4 + (threadIdx.x >> 6);
  if (row >= B) return;
  int lane = threadIdx.x & 63;
  size_t base = (size_t)row * DHID;
  RowCtx c = make_ctx(nhA[row], nxA[row]);

  float gh[16], gx[16], bb[16], st[16], out[16], sv[16];
  load_f32_row(state + base, lane, st);

  // z gate
  load_bf16_row(Gzh + base, lane, gh);
  load_bf16_row(Gzx + base, lane, gx);
  load_f32_row(bz, lane, bb);   // bias [1,DHID]: broadcast across rows
  gate_sig(gh, gx, bb, c, out, sv);
  #pragma unroll
  for (int j = 0; j < 4; ++j) {
    int idx = j * 64 + lane;
    ((float4*)(zout + base))[idx] = make_float4(out[4*j], out[4*j+1], out[4*j+2], out[4*j+3]);
  }

  // r gate
  load_bf16_row(Grh + base, lane, gh);
  load_bf16_row(Grx + base, lane, gx);
  load_f32_row(br, lane, bb);
  gate_sig(gh, gx, bb, c, out, sv);

  // r_point_h = project(mob_pw(state_proj, r), 1e-4)
  float mxv[16]; float s = 0.f;
  #pragma unroll
  for (int j = 0; j < 16; ++j) { mxv[j] = st[j] * c.scale_h * out[j]; s += mxv[j]*mxv[j]; }
  s = wred(s);
  float mxn = fmaxf(sqrtf(s), 1e-10f);
  float t = ftanh(mxn * frcp(c.hnc) * c.ath);
  float cc = t * frcp(mxn);
  float nrp = t;
  float psc = (nrp > 0.9999f) ? 0.9999f * frcp(nrp + 1e-10f) : 1.0f;
  cc *= psc; nrp *= psc;
  #pragma unroll
  for (int j = 0; j < 4; ++j) {
    int idx = j * 64 + lane;
    ((ushort4*)(rphb + base))[idx] = make_ushort4(
        f2bf(cc*mxv[4*j+0]), f2bf(cc*mxv[4*j+1]), f2bf(cc*mxv[4*j+2]), f2bf(cc*mxv[4*j+3]));
  }
  if (lane == 0) rnA[row] = nrp;
}

// ---------- final: h_tilde, update, new_h ----------
__global__ __launch_bounds__(256) void final_k(
    const u16* __restrict__ Ghh, const u16* __restrict__ Ghx,
    const float* __restrict__ state, const float* __restrict__ bh,
    const float* __restrict__ nxA, const float* __restrict__ nhA, const float* __restrict__ rnA,
    float* __restrict__ io, int B) {
  int row = blockIdx.x * 4 + (threadIdx.x >> 6);
  if (row >= B) return;
  int lane = threadIdx.x & 63;
  size_t base = (size_t)row * DHID;
  float n_h = nhA[row], n_x = nxA[row], rn = rnA[row];
  float scale_h = (n_h > 0.9999f) ? 0.9999f * frcp(n_h + 1e-10f) : 1.0f;
  float hn = n_h * scale_h;
  float nxc = fmaxf(n_x, 1e-10f);
  float scale_x = ftanh(nxc) * frcp(nxc);
  float xn = fmaxf(n_x * scale_x, 1e-10f);
  float atx = fatanh(xn);
  float hna = fmaxf(rn, 1e-10f);
  float atr = fatanh(rn);

  float gh[16], gx[16], bb[16], st[16], zz[16], sv[16];
  load_f32_row(state + base, lane, st);
  load_f32_row(io + base, lane, zz);   // z from gates_k
  load_bf16_row(Ghh + base, lane, gh);
  load_bf16_row(Ghx + base, lane, gx);
  load_f32_row(bh, lane, bb);

  // a = mob_matmul(r_point_h, Wh); b = mob_matmul(hyp_x, Uh)
  float sh = 0.f, sx = 0.f, dxy = 0.f;
  #pragma unroll
  for (int j = 0; j < 16; ++j) { sh += gh[j]*gh[j]; sx += gx[j]*gx[j]; dxy += gh[j]*gx[j]; }
  sh = wred(sh); sx = wred(sx); dxy = wred(dxy);
  float mhn = fmaxf(sqrtf(sh), 1e-10f);
  float ta = ftanh(mhn * frcp(hna) * atr);
  float ca = ta * frcp(mhn);
  float mxn = fmaxf(scale_x * sqrtf(sx), 1e-10f);
  float tb = ftanh(mxn * frcp(xn) * atx);
  float cb = tb * scale_x * frcp(mxn);
  float uv = ca * cb * dxy;
  float u2 = ta * ta, v2 = tb * tb;
  float rden = frcp(1.f + 2.f*uv + u2*v2 + 1e-10f);
  float c1 = (1.f + 2.f*uv + v2) * rden * ca;
  float c2 = (1.f - u2) * rden * cb;
  float uvb = 0.f, u2s = 0.f, v2b = 0.f;
  #pragma unroll
  for (int j = 0; j < 16; ++j) {
    sv[j] = c1 * gh[j] + c2 * gx[j];
    uvb += sv[j]*bb[j]; u2s += sv[j]*sv[j]; v2b += bb[j]*bb[j];
  }
  uvb = wred(uvb); u2s = wred(u2s); v2b = wred(v2b);
  float rden2 = frcp(1.f + 2.f*uvb + u2s*v2b + 1e-10f);
  float d1 = (1.f + 2.f*uvb + v2b) * rden2, d2 = (1.f - u2s) * rden2;
  float s3 = 0.f;
  #pragma unroll
  for (int j = 0; j < 16; ++j) { sv[j] = d1 * sv[j] + d2 * bb[j]; s3 += sv[j]*sv[j]; }
  s3 = wred(s3);
  float ns = sqrtf(s3);
  float p1 = (ns > 0.99999f) ? 0.99999f * frcp(ns + 1e-10f) : 1.0f;
  float n1 = ns * p1;
  float p2 = (n1 > 0.9999f) ? 0.9999f * frcp(n1 + 1e-10f) : 1.0f;
  float pc = p1 * p2;
  float nht = n1 * p2;
  #pragma unroll
  for (int j = 0; j < 16; ++j) sv[j] *= pc;   // sv = h_tilde

  // m = mob_add(-state_proj, h_tilde)
  float dv = 0.f;
  #pragma unroll
  for (int j = 0; j < 16; ++j) dv += st[j] * sv[j];
  dv = wred(dv);
  float uv2 = -scale_h * dv;
  float u2m = hn * hn, v2m = nht * nht;
  float rden3 = frcp(1.f + 2.f*uv2 + u2m*v2m + 1e-10f);
  float e1 = -(1.f + 2.f*uv2 + v2m) * rden3 * scale_h;  // * st
  float e2 = (1.f - u2m) * rden3;                       // * sv
  float mv[16]; float sm = 0.f;
  #pragma unroll
  for (int j = 0; j < 16; ++j) { mv[j] = e1*st[j] + e2*sv[j]; sm += mv[j]*mv[j]; }
  sm = wred(sm);
  float vn = fmaxf(sqrtf(sm), 1e-10f);
  float atv = fatanh(vn);
  // update = mob_pw(m, z)
  float mx2[16]; float s4 = 0.f;
  #pragma unroll
  for (int j = 0; j < 16; ++j) { mx2[j] = mv[j]*zz[j]; s4 += mx2[j]*mx2[j]; }
  s4 = wred(s4);
  float mxn2 = fmaxf(sqrtf(s4), 1e-10f);
  float tu = ftanh(mxn2 * frcp(vn) * atv);
  float cu2 = tu * frcp(mxn2);                          // upd = cu2*mx2
  // new_h = project(mob_add(state_proj, upd), 1e-5)
  float d5 = 0.f;
  #pragma unroll
  for (int j = 0; j < 16; ++j) d5 += st[j]*mx2[j];
  d5 = wred(d5);
  float uv3 = scale_h * cu2 * d5;
  float u2f = hn * hn, v2f = tu * tu;
  float rden4 = frcp(1.f + 2.f*uv3 + u2f*v2f + 1e-10f);
  float f1 = (1.f + 2.f*uv3 + v2f) * rden4 * scale_h;   // * st
  float f2 = (1.f - u2f) * rden4 * cu2;                 // * mx2
  float nh4[16]; float s5 = 0.f;
  #pragma unroll
  for (int j = 0; j < 16; ++j) { nh4[j] = f1*st[j] + f2*mx2[j]; s5 += nh4[j]*nh4[j]; }
  s5 = wred(s5);
  float nf = sqrtf(s5);
  float pf = (nf > 0.99999f) ? 0.99999f * frcp(nf + 1e-10f) : 1.0f;
  #pragma unroll
  for (int j = 0; j < 4; ++j) {
    int idx = j * 64 + lane;
    ((float4*)(io + base))[idx] = make_float4(pf*nh4[4*j], pf*nh4[4*j+1], pf*nh4[4*j+2], pf*nh4[4*j+3]);
  }
}

extern "C" void kernel_launch(void* const* d_in, const int* in_sizes, int n_in,
                              void* d_out, int out_size, void* d_ws, size_t ws_size,
                              hipStream_t stream) {
  const float* inputs = (const float*)d_in[0];
  const float* state  = (const float*)d_in[1];
  const float* Wz = (const float*)d_in[2];
  const float* Uz = (const float*)d_in[3];
  const float* bz = (const float*)d_in[4];
  const float* Wr = (const float*)d_in[5];
  const float* Ur = (const float*)d_in[6];
  const float* br = (const float*)d_in[7];
  const float* Wh = (const float*)d_in[8];
  const float* Uh = (const float*)d_in[9];
  const float* bh = (const float*)d_in[10];
  const int B = in_sizes[0] / DHID;
  const size_t MD = (size_t)B * DHID;

  char* p = (char*)d_ws;
  u16* xb = (u16*)p;  p += MD * 2;
  u16* hb = (u16*)p;  p += MD * 2;            // state bf16, later r_point_h bf16
  u16* Wt0 = (u16*)p; p += (size_t)DHID*DHID*2;
  u16* Wt1 = (u16*)p; p += (size_t)DHID*DHID*2;
  u16* Wt2 = (u16*)p; p += (size_t)DHID*DHID*2;
  u16* Wt3 = (u16*)p; p += (size_t)DHID*DHID*2;
  u16* Wt4 = (u16*)p; p += (size_t)DHID*DHID*2;
  u16* Wt5 = (u16*)p; p += (size_t)DHID*DHID*2;
  u16* G0 = (u16*)p;  p += MD * 2;
  u16* G1 = (u16*)p;  p += MD * 2;
  u16* G2 = (u16*)p;  p += MD * 2;
  u16* G3 = (u16*)p;  p += MD * 2;
  float* nx = (float*)p; p += (size_t)B * 4;
  float* nh = (float*)p; p += (size_t)B * 4;
  float* rn = (float*)p; p += (size_t)B * 4;
  if ((size_t)(p - (char*)d_ws) > ws_size) return;

  float* zbuf = (float*)d_out;

  prep<<<B/4, 256, 0, stream>>>(inputs, state, xb, hb, nx, nh, B);

  W6 wp;
  wp.s[0] = Wz; wp.s[1] = Wr; wp.s[2] = Wh; wp.s[3] = Uz; wp.s[4] = Ur; wp.s[5] = Uh;
  wp.d[0] = Wt0; wp.d[1] = Wt1; wp.d[2] = Wt2; wp.d[3] = Wt3; wp.d[4] = Wt4; wp.d[5] = Wt5;
  dim3 tb(32, 8), tg(DHID/32, DHID/32, 6);
  wconv_all<<<tg, tb, 0, stream>>>(wp);

  dim3 gg(B/128, DHID/128);
  gemm_bf16<<<gg, 256, 0, stream>>>(hb, Wt0, G0, B, DHID, DHID);  // state@Wz
  gemm_bf16<<<gg, 256, 0, stream>>>(hb, Wt1, G1, B, DHID, DHID);  // state@Wr
  gemm_bf16<<<gg, 256, 0, stream>>>(xb, Wt3, G2, B, DHID, DHID);  // inputs@Uz
  gemm_bf16<<<gg, 256, 0, stream>>>(xb, Wt4, G3, B, DHID, DHID);  // inputs@Ur

  gates_k<<<B/4, 256, 0, stream>>>(G0, G2, G1, G3, state, bz, br, nx, nh, zbuf, hb, rn, B);

  gemm_bf16<<<gg, 256, 0, stream>>>(hb, Wt2, G0, B, DHID, DHID);  // r_point_h@Wh
  gemm_bf16<<<gg, 256, 0, stream>>>(xb, Wt5, G1, B, DHID, DHID);  // inputs@Uh

  final_k<<<B/4, 256, 0, stream>>>(G0, G1, state, bh, nx, nh, rn, zbuf, B);
}

// Round 5
// 393.574 us; speedup vs baseline: 1.2412x; 1.2412x over previous
//
#include <hip/hip_runtime.h>
#include <math.h>

typedef unsigned short u16;
typedef __attribute__((ext_vector_type(8))) short bf16x8;
typedef __attribute__((ext_vector_type(4))) float f32x4;

#define DHID 1024

__device__ __forceinline__ u16 f2bf(float f) {
  union { float f; unsigned u; } v; v.f = f;
  unsigned u = v.u;
  u = (u + 0x7fffu + ((u >> 16) & 1u)) >> 16;
  return (u16)u;
}
__device__ __forceinline__ float bf2f(u16 h) {
  union { unsigned u; float f; } v; v.u = ((unsigned)h) << 16;
  return v.f;
}
__device__ __forceinline__ float wred(float v) {
  #pragma unroll
  for (int m = 32; m > 0; m >>= 1) v += __shfl_xor(v, m, 64);
  return v;
}
// ---- fast math: v_rcp_f32 / v_exp_f32 / v_log_f32 based ----
__device__ __forceinline__ float frcp(float x) { return __builtin_amdgcn_rcpf(x); }
__device__ __forceinline__ float ftanh(float x) {
  x = fminf(fmaxf(x, -15.f), 15.f);            // tanh(15) = 1 - 1e-13; avoids inf*0
  float t = __expf(2.f * x);
  return (t - 1.f) * frcp(t + 1.f);
}
__device__ __forceinline__ float fatanh(float x) {   // includes EPS clamp of reference
  x = fminf(fmaxf(x, -1.0f + 1e-5f), 1.0f - 1e-5f);
  return 0.5f * __logf((1.f + x) * frcp(1.f - x));
}
__device__ __forceinline__ float fsig(float x) {     // 1/(1+e^-x)
  return frcp(1.f + __expf(-x));
}

// ---------- fused weight convert+transpose for all 6: dst[n][k] = bf16(src[k][n]) ----------
struct W6 { const float* s[6]; u16* d[6]; };
__global__ __launch_bounds__(256) void wconv_all(W6 p) {
  const float* __restrict__ src = p.s[blockIdx.z];
  u16* __restrict__ dst = p.d[blockIdx.z];
  __shared__ float t[32][33];
  int bx = blockIdx.x * 32, by = blockIdx.y * 32;
  int tx = threadIdx.x, ty = threadIdx.y;
  #pragma unroll
  for (int r = 0; r < 32; r += 8)
    t[ty + r][tx] = src[(size_t)(by + ty + r) * DHID + bx + tx];
  __syncthreads();
  #pragma unroll
  for (int r = 0; r < 32; r += 8)
    dst[(size_t)(bx + ty + r) * DHID + by + tx] = f2bf(t[tx][ty + r]);
}

// ---------- prep: row norms + bf16 casts ----------
__global__ __launch_bounds__(256) void prep(const float* __restrict__ x, const float* __restrict__ h,
    u16* __restrict__ xb, u16* __restrict__ hb, float* __restrict__ nx, float* __restrict__ nh, int B) {
  int row = blockIdx.x * 4 + (threadIdx.x >> 6);
  if (row >= B) return;
  int lane = threadIdx.x & 63;
  size_t base = (size_t)row * DHID;
  const float4* xr = (const float4*)(x + base);
  const float4* hr = (const float4*)(h + base);
  ushort4* xo = (ushort4*)(xb + base);
  ushort4* ho = (ushort4*)(hb + base);
  float sx = 0.f, sh = 0.f;
  #pragma unroll
  for (int j = 0; j < 4; ++j) {
    int idx = j * 64 + lane;
    float4 a = xr[idx], b = hr[idx];
    sx += a.x*a.x + a.y*a.y + a.z*a.z + a.w*a.w;
    sh += b.x*b.x + b.y*b.y + b.z*b.z + b.w*b.w;
    xo[idx] = make_ushort4(f2bf(a.x), f2bf(a.y), f2bf(a.z), f2bf(a.w));
    ho[idx] = make_ushort4(f2bf(b.x), f2bf(b.y), f2bf(b.z), f2bf(b.w));
  }
  sx = wred(sx); sh = wred(sh);
  if (lane == 0) { nx[row] = sqrtf(sx); nh[row] = sqrtf(sh); }
}

// ---------- async global->LDS staging helper (width 16B) ----------
__device__ __forceinline__ void gll16(const void* g, void* l) {
  __builtin_amdgcn_global_load_lds((const __attribute__((address_space(1))) unsigned int*)g,
                                   (__attribute__((address_space(3))) unsigned int*)l, 16, 0, 0);
}

// ---------- batched bf16 MFMA GEMM: C[M][N] = A[M][K] @ Bt[N][K]^T ----------
// LDS layout: linear rows of 64 u16 (global_load_lds requires linear dest), but the
// STORED layout is XOR-swizzled (st-16x... style): physical u16 col p of row r holds
// logical col p ^ ((r&7)<<3). Achieved by pre-swizzling the per-lane GLOBAL source
// column (m173 pattern); reads apply the same XOR -> 2-way max on ds_read_b128 (free).
struct GB { const u16* A[4]; const u16* Bt[4]; u16* C[4]; };
__global__ __launch_bounds__(256) void gemm_bf16(GB gb, int M, int N, int K) {
  const u16* __restrict__ A  = gb.A[blockIdx.z];
  const u16* __restrict__ Bt = gb.Bt[blockIdx.z];
  u16* __restrict__ C        = gb.C[blockIdx.z];
  __shared__ __align__(16) u16 As[128 * 64];
  __shared__ __align__(16) u16 Bs[128 * 64];
  const int tid = threadIdx.x;
  const int lane = tid & 63;
  const int wid = tid >> 6;
  const int wr = (wid >> 1) * 64;
  const int wc = (wid & 1) * 64;
  const int l15 = lane & 15;
  const int koff = (lane >> 4) * 8;
  const int cswz = (l15 & 7) << 3;            // read-side XOR (u16 units)
  // staging geometry: lane covers row srow of an 8-row chunk, 16B chunk scol
  const int srow = lane >> 3;                  // 0..7
  const int scol = ((lane & 7) ^ srow) * 8;    // pre-swizzled global u16 col
  const size_t abase = (size_t)(blockIdx.x * 128) * K;
  const size_t bbase = (size_t)(blockIdx.y * 128) * K;
  f32x4 acc[4][4] = {};
  for (int k0 = 0; k0 < K; k0 += 64) {
    __syncthreads();   // previous tile fully consumed
    #pragma unroll
    for (int i = 0; i < 4; ++i) {
      int rb = (i * 4 + wid) * 8;
      gll16(A  + abase + (size_t)(rb + srow) * K + k0 + scol, &As[rb * 64]);
      gll16(Bt + bbase + (size_t)(rb + srow) * K + k0 + scol, &Bs[rb * 64]);
    }
    __syncthreads();   // compiler drains vmcnt(0) before barrier
    #pragma unroll
    for (int ks = 0; ks < 64; ks += 32) {
      bf16x8 af[4], bg[4];
      #pragma unroll
      for (int m = 0; m < 4; ++m)
        af[m] = *(const bf16x8*)&As[(wr + m*16 + l15) * 64 + ((ks + koff) ^ cswz)];
      #pragma unroll
      for (int n = 0; n < 4; ++n)
        bg[n] = *(const bf16x8*)&Bs[(wc + n*16 + l15) * 64 + ((ks + koff) ^ cswz)];
      #pragma unroll
      for (int m = 0; m < 4; ++m)
        #pragma unroll
        for (int n = 0; n < 4; ++n)
          acc[m][n] = __builtin_amdgcn_mfma_f32_16x16x32_bf16(af[m], bg[n], acc[m][n], 0, 0, 0);
    }
  }
  const int r4 = (lane >> 4) * 4;
  #pragma unroll
  for (int m = 0; m < 4; ++m)
    #pragma unroll
    for (int n = 0; n < 4; ++n) {
      size_t col = (size_t)blockIdx.y * 128 + wc + n * 16 + l15;
      #pragma unroll
      for (int j = 0; j < 4; ++j) {
        size_t row = (size_t)blockIdx.x * 128 + wr + m * 16 + r4 + j;
        C[row * N + col] = f2bf(acc[m][n][j]);
      }
    }
}

// ---------- row helpers ----------
__device__ __forceinline__ void load_bf16_row(const u16* p, int lane, float v[16]) {
  #pragma unroll
  for (int j = 0; j < 4; ++j) {
    int idx = j * 64 + lane;
    ushort4 a = ((const ushort4*)p)[idx];
    v[4*j+0] = bf2f(a.x); v[4*j+1] = bf2f(a.y); v[4*j+2] = bf2f(a.z); v[4*j+3] = bf2f(a.w);
  }
}
__device__ __forceinline__ void load_f32_row(const float* p, int lane, float v[16]) {
  #pragma unroll
  for (int j = 0; j < 4; ++j) {
    int idx = j * 64 + lane;
    float4 a = ((const float4*)p)[idx];
    v[4*j+0] = a.x; v[4*j+1] = a.y; v[4*j+2] = a.z; v[4*j+3] = a.w;
  }
}

struct RowCtx {
  float scale_h, hnc, ath, scale_x, xn, atx;
};

__device__ __forceinline__ RowCtx make_ctx(float n_h, float n_x) {
  RowCtx c;
  c.scale_h = (n_h > 0.9999f) ? 0.9999f * frcp(n_h + 1e-10f) : 1.0f;
  float hn = n_h * c.scale_h;
  c.hnc = fmaxf(hn, 1e-10f);
  c.ath = fatanh(hn);
  float nxc = fmaxf(n_x, 1e-10f);
  c.scale_x = ftanh(nxc) * frcp(nxc);
  c.xn = fmaxf(n_x * c.scale_x, 1e-10f);
  c.atx = fatanh(c.xn);
  return c;
}

// one_transform + log0 + sigmoid for one gate (gh = state_raw@W, gx = inputs_raw@U)
__device__ __forceinline__ void gate_sig(const float gh[16], const float gx[16], const float bb[16],
                                         const RowCtx& c, float out[16], float sv[16]) {
  float sh = 0.f, sx = 0.f, dxy = 0.f;
  #pragma unroll
  for (int j = 0; j < 16; ++j) { sh += gh[j]*gh[j]; sx += gx[j]*gx[j]; dxy += gh[j]*gx[j]; }
  sh = wred(sh); sx = wred(sx); dxy = wred(dxy);
  float mhn = fmaxf(c.scale_h * sqrtf(sh), 1e-10f);
  float th  = ftanh(mhn * frcp(c.hnc) * c.ath);
  float ca  = th * c.scale_h * frcp(mhn);      // u[j] = ca*gh[j]
  float mxn = fmaxf(c.scale_x * sqrtf(sx), 1e-10f);
  float tx  = ftanh(mxn * frcp(c.xn) * c.atx);
  float cb  = tx * c.scale_x * frcp(mxn);      // v[j] = cb*gx[j]
  float uv = ca * cb * dxy;
  float u2 = th * th, v2 = tx * tx;
  float rden = frcp(1.f + 2.f*uv + u2*v2 + 1e-10f);
  float c1 = (1.f + 2.f*uv + v2) * rden * ca;
  float c2 = (1.f - u2) * rden * cb;
  float uvb = 0.f, u2s = 0.f, v2b = 0.f;
  #pragma unroll
  for (int j = 0; j < 16; ++j) {
    sv[j] = c1 * gh[j] + c2 * gx[j];
    uvb += sv[j] * bb[j]; u2s += sv[j] * sv[j]; v2b += bb[j] * bb[j];
  }
  uvb = wred(uvb); u2s = wred(u2s); v2b = wred(v2b);
  float rden2 = frcp(1.f + 2.f*uvb + u2s*v2b + 1e-10f);
  float d1 = (1.f + 2.f*uvb + v2b) * rden2, d2 = (1.f - u2s) * rden2;
  float s3 = 0.f;
  #pragma unroll
  for (int j = 0; j < 16; ++j) { sv[j] = d1 * sv[j] + d2 * bb[j]; s3 += sv[j]*sv[j]; }
  s3 = wred(s3);
  float ns = sqrtf(s3);
  float ps = (ns > 0.99999f) ? 0.99999f * frcp(ns + 1e-10f) : 1.0f;
  float nres = fmaxf(ns * ps, 1e-10f);
  float g = fatanh(nres) * frcp(nres) * ps;
  #pragma unroll
  for (int j = 0; j < 16; ++j) out[j] = fsig(g * sv[j]);
}

// ---------- gates: z (-> d_out), r, r_point_h (-> bf16), rn ----------
__global__ __launch_bounds__(256) void gates_k(
    const u16* __restrict__ Gzh, const u16* __restrict__ Gzx,
    const u16* __restrict__ Grh, const u16* __restrict__ Grx,
    const float* __restrict__ state, const float* __restrict__ bz, const float* __restrict__ br,
    const float* __restrict__ nxA, const float* __restrict__ nhA,
    float* __restrict__ zout, u16* __restrict__ rphb, float* __restrict__ rnA, int B) {
  int row = blockIdx.x * 4 + (threadIdx.x >> 6);
  if (row >= B) return;
  int lane = threadIdx.x & 63;
  size_t base = (size_t)row * DHID;
  RowCtx c = make_ctx(nhA[row], nxA[row]);

  float gh[16], gx[16], bb[16], st[16], out[16], sv[16];
  load_f32_row(state + base, lane, st);

  // z gate
  load_bf16_row(Gzh + base, lane, gh);
  load_bf16_row(Gzx + base, lane, gx);
  load_f32_row(bz, lane, bb);   // bias [1,DHID]: broadcast across rows
  gate_sig(gh, gx, bb, c, out, sv);
  #pragma unroll
  for (int j = 0; j < 4; ++j) {
    int idx = j * 64 + lane;
    ((float4*)(zout + base))[idx] = make_float4(out[4*j], out[4*j+1], out[4*j+2], out[4*j+3]);
  }

  // r gate
  load_bf16_row(Grh + base, lane, gh);
  load_bf16_row(Grx + base, lane, gx);
  load_f32_row(br, lane, bb);
  gate_sig(gh, gx, bb, c, out, sv);

  // r_point_h = project(mob_pw(state_proj, r), 1e-4)
  float mxv[16]; float s = 0.f;
  #pragma unroll
  for (int j = 0; j < 16; ++j) { mxv[j] = st[j] * c.scale_h * out[j]; s += mxv[j]*mxv[j]; }
  s = wred(s);
  float mxn = fmaxf(sqrtf(s), 1e-10f);
  float t = ftanh(mxn * frcp(c.hnc) * c.ath);
  float cc = t * frcp(mxn);
  float nrp = t;
  float psc = (nrp > 0.9999f) ? 0.9999f * frcp(nrp + 1e-10f) : 1.0f;
  cc *= psc; nrp *= psc;
  #pragma unroll
  for (int j = 0; j < 4; ++j) {
    int idx = j * 64 + lane;
    ((ushort4*)(rphb + base))[idx] = make_ushort4(
        f2bf(cc*mxv[4*j+0]), f2bf(cc*mxv[4*j+1]), f2bf(cc*mxv[4*j+2]), f2bf(cc*mxv[4*j+3]));
  }
  if (lane == 0) rnA[row] = nrp;
}

// ---------- final: h_tilde, update, new_h ----------
__global__ __launch_bounds__(256) void final_k(
    const u16* __restrict__ Ghh, const u16* __restrict__ Ghx,
    const float* __restrict__ state, const float* __restrict__ bh,
    const float* __restrict__ nxA, const float* __restrict__ nhA, const float* __restrict__ rnA,
    float* __restrict__ io, int B) {
  int row = blockIdx.x * 4 + (threadIdx.x >> 6);
  if (row >= B) return;
  int lane = threadIdx.x & 63;
  size_t base = (size_t)row * DHID;
  float n_h = nhA[row], n_x = nxA[row], rn = rnA[row];
  float scale_h = (n_h > 0.9999f) ? 0.9999f * frcp(n_h + 1e-10f) : 1.0f;
  float hn = n_h * scale_h;
  float nxc = fmaxf(n_x, 1e-10f);
  float scale_x = ftanh(nxc) * frcp(nxc);
  float xn = fmaxf(n_x * scale_x, 1e-10f);
  float atx = fatanh(xn);
  float hna = fmaxf(rn, 1e-10f);
  float atr = fatanh(rn);

  float gh[16], gx[16], bb[16], st[16], zz[16], sv[16];
  load_f32_row(state + base, lane, st);
  load_f32_row(io + base, lane, zz);   // z from gates_k
  load_bf16_row(Ghh + base, lane, gh);
  load_bf16_row(Ghx + base, lane, gx);
  load_f32_row(bh, lane, bb);

  // a = mob_matmul(r_point_h, Wh); b = mob_matmul(hyp_x, Uh)
  float sh = 0.f, sx = 0.f, dxy = 0.f;
  #pragma unroll
  for (int j = 0; j < 16; ++j) { sh += gh[j]*gh[j]; sx += gx[j]*gx[j]; dxy += gh[j]*gx[j]; }
  sh = wred(sh); sx = wred(sx); dxy = wred(dxy);
  float mhn = fmaxf(sqrtf(sh), 1e-10f);
  float ta = ftanh(mhn * frcp(hna) * atr);
  float ca = ta * frcp(mhn);
  float mxn = fmaxf(scale_x * sqrtf(sx), 1e-10f);
  float tb = ftanh(mxn * frcp(xn) * atx);
  float cb = tb * scale_x * frcp(mxn);
  float uv = ca * cb * dxy;
  float u2 = ta * ta, v2 = tb * tb;
  float rden = frcp(1.f + 2.f*uv + u2*v2 + 1e-10f);
  float c1 = (1.f + 2.f*uv + v2) * rden * ca;
  float c2 = (1.f - u2) * rden * cb;
  float uvb = 0.f, u2s = 0.f, v2b = 0.f;
  #pragma unroll
  for (int j = 0; j < 16; ++j) {
    sv[j] = c1 * gh[j] + c2 * gx[j];
    uvb += sv[j]*bb[j]; u2s += sv[j]*sv[j]; v2b += bb[j]*bb[j];
  }
  uvb = wred(uvb); u2s = wred(u2s); v2b = wred(v2b);
  float rden2 = frcp(1.f + 2.f*uvb + u2s*v2b + 1e-10f);
  float d1 = (1.f + 2.f*uvb + v2b) * rden2, d2 = (1.f - u2s) * rden2;
  float s3 = 0.f;
  #pragma unroll
  for (int j = 0; j < 16; ++j) { sv[j] = d1 * sv[j] + d2 * bb[j]; s3 += sv[j]*sv[j]; }
  s3 = wred(s3);
  float ns = sqrtf(s3);
  float p1 = (ns > 0.99999f) ? 0.99999f * frcp(ns + 1e-10f) : 1.0f;
  float n1 = ns * p1;
  float p2 = (n1 > 0.9999f) ? 0.9999f * frcp(n1 + 1e-10f) : 1.0f;
  float pc = p1 * p2;
  float nht = n1 * p2;
  #pragma unroll
  for (int j = 0; j < 16; ++j) sv[j] *= pc;   // sv = h_tilde

  // m = mob_add(-state_proj, h_tilde)
  float dv = 0.f;
  #pragma unroll
  for (int j = 0; j < 16; ++j) dv += st[j] * sv[j];
  dv = wred(dv);
  float uv2 = -scale_h * dv;
  float u2m = hn * hn, v2m = nht * nht;
  float rden3 = frcp(1.f + 2.f*uv2 + u2m*v2m + 1e-10f);
  float e1 = -(1.f + 2.f*uv2 + v2m) * rden3 * scale_h;  // * st
  float e2 = (1.f - u2m) * rden3;                       // * sv
  float mv[16]; float sm = 0.f;
  #pragma unroll
  for (int j = 0; j < 16; ++j) { mv[j] = e1*st[j] + e2*sv[j]; sm += mv[j]*mv[j]; }
  sm = wred(sm);
  float vn = fmaxf(sqrtf(sm), 1e-10f);
  float atv = fatanh(vn);
  // update = mob_pw(m, z)
  float mx2[16]; float s4 = 0.f;
  #pragma unroll
  for (int j = 0; j < 16; ++j) { mx2[j] = mv[j]*zz[j]; s4 += mx2[j]*mx2[j]; }
  s4 = wred(s4);
  float mxn2 = fmaxf(sqrtf(s4), 1e-10f);
  float tu = ftanh(mxn2 * frcp(vn) * atv);
  float cu2 = tu * frcp(mxn2);                          // upd = cu2*mx2
  // new_h = project(mob_add(state_proj, upd), 1e-5)
  float d5 = 0.f;
  #pragma unroll
  for (int j = 0; j < 16; ++j) d5 += st[j]*mx2[j];
  d5 = wred(d5);
  float uv3 = scale_h * cu2 * d5;
  float u2f = hn * hn, v2f = tu * tu;
  float rden4 = frcp(1.f + 2.f*uv3 + u2f*v2f + 1e-10f);
  float f1 = (1.f + 2.f*uv3 + v2f) * rden4 * scale_h;   // * st
  float f2 = (1.f - u2f) * rden4 * cu2;                 // * mx2
  float nh4[16]; float s5 = 0.f;
  #pragma unroll
  for (int j = 0; j < 16; ++j) { nh4[j] = f1*st[j] + f2*mx2[j]; s5 += nh4[j]*nh4[j]; }
  s5 = wred(s5);
  float nf = sqrtf(s5);
  float pf = (nf > 0.99999f) ? 0.99999f * frcp(nf + 1e-10f) : 1.0f;
  #pragma unroll
  for (int j = 0; j < 4; ++j) {
    int idx = j * 64 + lane;
    ((float4*)(io + base))[idx] = make_float4(pf*nh4[4*j], pf*nh4[4*j+1], pf*nh4[4*j+2], pf*nh4[4*j+3]);
  }
}

extern "C" void kernel_launch(void* const* d_in, const int* in_sizes, int n_in,
                              void* d_out, int out_size, void* d_ws, size_t ws_size,
                              hipStream_t stream) {
  const float* inputs = (const float*)d_in[0];
  const float* state  = (const float*)d_in[1];
  const float* Wz = (const float*)d_in[2];
  const float* Uz = (const float*)d_in[3];
  const float* bz = (const float*)d_in[4];
  const float* Wr = (const float*)d_in[5];
  const float* Ur = (const float*)d_in[6];
  const float* br = (const float*)d_in[7];
  const float* Wh = (const float*)d_in[8];
  const float* Uh = (const float*)d_in[9];
  const float* bh = (const float*)d_in[10];
  const int B = in_sizes[0] / DHID;
  const size_t MD = (size_t)B * DHID;

  char* p = (char*)d_ws;
  u16* xb = (u16*)p;  p += MD * 2;
  u16* hb = (u16*)p;  p += MD * 2;            // state bf16, later r_point_h bf16
  u16* Wt0 = (u16*)p; p += (size_t)DHID*DHID*2;
  u16* Wt1 = (u16*)p; p += (size_t)DHID*DHID*2;
  u16* Wt2 = (u16*)p; p += (size_t)DHID*DHID*2;
  u16* Wt3 = (u16*)p; p += (size_t)DHID*DHID*2;
  u16* Wt4 = (u16*)p; p += (size_t)DHID*DHID*2;
  u16* Wt5 = (u16*)p; p += (size_t)DHID*DHID*2;
  u16* G0 = (u16*)p;  p += MD * 2;
  u16* G1 = (u16*)p;  p += MD * 2;
  u16* G2 = (u16*)p;  p += MD * 2;
  u16* G3 = (u16*)p;  p += MD * 2;
  float* nx = (float*)p; p += (size_t)B * 4;
  float* nh = (float*)p; p += (size_t)B * 4;
  float* rn = (float*)p; p += (size_t)B * 4;
  if ((size_t)(p - (char*)d_ws) > ws_size) return;

  float* zbuf = (float*)d_out;

  prep<<<B/4, 256, 0, stream>>>(inputs, state, xb, hb, nx, nh, B);

  W6 wp;
  wp.s[0] = Wz; wp.s[1] = Wr; wp.s[2] = Wh; wp.s[3] = Uz; wp.s[4] = Ur; wp.s[5] = Uh;
  wp.d[0] = Wt0; wp.d[1] = Wt1; wp.d[2] = Wt2; wp.d[3] = Wt3; wp.d[4] = Wt4; wp.d[5] = Wt5;
  dim3 tb(32, 8), tg(DHID/32, DHID/32, 6);
  wconv_all<<<tg, tb, 0, stream>>>(wp);

  // stage 1: 4 independent GEMMs in one dispatch
  GB g1;
  g1.A[0] = hb; g1.Bt[0] = Wt0; g1.C[0] = G0;   // state@Wz
  g1.A[1] = hb; g1.Bt[1] = Wt1; g1.C[1] = G1;   // state@Wr
  g1.A[2] = xb; g1.Bt[2] = Wt3; g1.C[2] = G2;   // inputs@Uz
  g1.A[3] = xb; g1.Bt[3] = Wt4; g1.C[3] = G3;   // inputs@Ur
  dim3 gg1(B/128, DHID/128, 4);
  gemm_bf16<<<gg1, 256, 0, stream>>>(g1, B, DHID, DHID);

  gates_k<<<B/4, 256, 0, stream>>>(G0, G2, G1, G3, state, bz, br, nx, nh, zbuf, hb, rn, B);

  // stage 2: 2 GEMMs in one dispatch
  GB g2;
  g2.A[0] = hb; g2.Bt[0] = Wt2; g2.C[0] = G0;   // r_point_h@Wh
  g2.A[1] = xb; g2.Bt[1] = Wt5; g2.C[1] = G1;   // inputs@Uh
  g2.A[2] = hb; g2.Bt[2] = Wt2; g2.C[2] = G0;   // (unused lanes guard)
  g2.A[3] = xb; g2.Bt[3] = Wt5; g2.C[3] = G1;
  dim3 gg2(B/128, DHID/128, 2);
  gemm_bf16<<<gg2, 256, 0, stream>>>(g2, B, DHID, DHID);

  final_k<<<B/4, 256, 0, stream>>>(G0, G1, state, bh, nx, nh, rn, zbuf, B);
}

// Round 6
// 382.439 us; speedup vs baseline: 1.2774x; 1.0291x over previous
//
#include <hip/hip_runtime.h>
#include <math.h>

typedef unsigned short u16;
typedef __attribute__((ext_vector_type(8))) short bf16x8;
typedef __attribute__((ext_vector_type(4))) float f32x4;

#define DHID 1024

__device__ __forceinline__ u16 f2bf(float f) {
  union { float f; unsigned u; } v; v.f = f;
  unsigned u = v.u;
  u = (u + 0x7fffu + ((u >> 16) & 1u)) >> 16;
  return (u16)u;
}
__device__ __forceinline__ float bf2f(u16 h) {
  union { unsigned u; float f; } v; v.u = ((unsigned)h) << 16;
  return v.f;
}
__device__ __forceinline__ float wred(float v) {
  #pragma unroll
  for (int m = 32; m > 0; m >>= 1) v += __shfl_xor(v, m, 64);
  return v;
}
// ---- fast math: v_rcp_f32 / v_exp_f32 / v_log_f32 based ----
__device__ __forceinline__ float frcp(float x) { return __builtin_amdgcn_rcpf(x); }
__device__ __forceinline__ float ftanh(float x) {
  x = fminf(fmaxf(x, -15.f), 15.f);            // tanh(15) = 1 - 1e-13; avoids inf*0
  float t = __expf(2.f * x);
  return (t - 1.f) * frcp(t + 1.f);
}
__device__ __forceinline__ float fatanh(float x) {   // includes EPS clamp of reference
  x = fminf(fmaxf(x, -1.0f + 1e-5f), 1.0f - 1e-5f);
  return 0.5f * __logf((1.f + x) * frcp(1.f - x));
}
__device__ __forceinline__ float fsig(float x) {     // 1/(1+e^-x)
  return frcp(1.f + __expf(-x));
}

// ---------- fused weight convert+transpose for all 6: dst[n][k] = bf16(src[k][n]) ----------
struct W6 { const float* s[6]; u16* d[6]; };
__global__ __launch_bounds__(256) void wconv_all(W6 p) {
  const float* __restrict__ src = p.s[blockIdx.z];
  u16* __restrict__ dst = p.d[blockIdx.z];
  __shared__ float t[32][33];
  int bx = blockIdx.x * 32, by = blockIdx.y * 32;
  int tx = threadIdx.x, ty = threadIdx.y;
  #pragma unroll
  for (int r = 0; r < 32; r += 8)
    t[ty + r][tx] = src[(size_t)(by + ty + r) * DHID + bx + tx];
  __syncthreads();
  #pragma unroll
  for (int r = 0; r < 32; r += 8)
    dst[(size_t)(bx + ty + r) * DHID + by + tx] = f2bf(t[tx][ty + r]);
}

// ---------- prep: row norms + bf16 casts ----------
__global__ __launch_bounds__(256) void prep(const float* __restrict__ x, const float* __restrict__ h,
    u16* __restrict__ xb, u16* __restrict__ hb, float* __restrict__ nx, float* __restrict__ nh, int B) {
  int row = blockIdx.x * 4 + (threadIdx.x >> 6);
  if (row >= B) return;
  int lane = threadIdx.x & 63;
  size_t base = (size_t)row * DHID;
  const float4* xr = (const float4*)(x + base);
  const float4* hr = (const float4*)(h + base);
  ushort4* xo = (ushort4*)(xb + base);
  ushort4* ho = (ushort4*)(hb + base);
  float sx = 0.f, sh = 0.f;
  #pragma unroll
  for (int j = 0; j < 4; ++j) {
    int idx = j * 64 + lane;
    float4 a = xr[idx], b = hr[idx];
    sx += a.x*a.x + a.y*a.y + a.z*a.z + a.w*a.w;
    sh += b.x*b.x + b.y*b.y + b.z*b.z + b.w*b.w;
    xo[idx] = make_ushort4(f2bf(a.x), f2bf(a.y), f2bf(a.z), f2bf(a.w));
    ho[idx] = make_ushort4(f2bf(b.x), f2bf(b.y), f2bf(b.z), f2bf(b.w));
  }
  sx = wred(sx); sh = wred(sh);
  if (lane == 0) { nx[row] = sqrtf(sx); nh[row] = sqrtf(sh); }
}

// ---------- async global->LDS staging helper (width 16B) ----------
__device__ __forceinline__ void gll16(const void* g, void* l) {
  __builtin_amdgcn_global_load_lds((const __attribute__((address_space(1))) unsigned int*)g,
                                   (__attribute__((address_space(3))) unsigned int*)l, 16, 0, 0);
}

// ---------- batched bf16 MFMA GEMM: C[.][ldC] col-block x, row-block y ----------
// C[row][col] = sum_k A[row][k] * Bt[col][k].  grid.x = N/128 (fastest: consecutive
// blocks share the A panel -> L2/L3 reuse), grid.y = M/128, grid.z = batch.
// LDS stored layout XOR-swizzled via pre-swizzled GLOBAL source col (m173 pattern);
// reads apply same XOR -> 0 bank conflicts (verified in round-5 PMC).
struct GB { const u16* A[2]; const u16* Bt[2]; u16* C[2]; };
__global__ __launch_bounds__(256) void gemm_bf16(GB gb, int K, int ldC) {
  const u16* __restrict__ A  = gb.A[blockIdx.z];
  const u16* __restrict__ Bt = gb.Bt[blockIdx.z];
  u16* __restrict__ C        = gb.C[blockIdx.z];
  __shared__ __align__(16) u16 As[128 * 64];
  __shared__ __align__(16) u16 Bs[128 * 64];
  const int tid = threadIdx.x;
  const int lane = tid & 63;
  const int wid = tid >> 6;
  const int wr = (wid >> 1) * 64;
  const int wc = (wid & 1) * 64;
  const int l15 = lane & 15;
  const int koff = (lane >> 4) * 8;
  const int cswz = (l15 & 7) << 3;            // read-side XOR (u16 units)
  const int srow = lane >> 3;                  // 0..7 within 8-row chunk
  const int scol = ((lane & 7) ^ srow) * 8;    // pre-swizzled global u16 col
  const size_t abase = (size_t)(blockIdx.y * 128) * K;
  const size_t bbase = (size_t)(blockIdx.x * 128) * K;
  f32x4 acc[4][4] = {};
  for (int k0 = 0; k0 < K; k0 += 64) {
    __syncthreads();   // previous tile fully consumed
    #pragma unroll
    for (int i = 0; i < 4; ++i) {
      int rb = (i * 4 + wid) * 8;
      gll16(A  + abase + (size_t)(rb + srow) * K + k0 + scol, &As[rb * 64]);
      gll16(Bt + bbase + (size_t)(rb + srow) * K + k0 + scol, &Bs[rb * 64]);
    }
    __syncthreads();   // compiler drains vmcnt(0) before barrier
    #pragma unroll
    for (int ks = 0; ks < 64; ks += 32) {
      bf16x8 af[4], bg[4];
      #pragma unroll
      for (int m = 0; m < 4; ++m)
        af[m] = *(const bf16x8*)&As[(wr + m*16 + l15) * 64 + ((ks + koff) ^ cswz)];
      #pragma unroll
      for (int n = 0; n < 4; ++n)
        bg[n] = *(const bf16x8*)&Bs[(wc + n*16 + l15) * 64 + ((ks + koff) ^ cswz)];
      #pragma unroll
      for (int m = 0; m < 4; ++m)
        #pragma unroll
        for (int n = 0; n < 4; ++n)
          acc[m][n] = __builtin_amdgcn_mfma_f32_16x16x32_bf16(af[m], bg[n], acc[m][n], 0, 0, 0);
    }
  }
  const int r4 = (lane >> 4) * 4;
  #pragma unroll
  for (int m = 0; m < 4; ++m)
    #pragma unroll
    for (int n = 0; n < 4; ++n) {
      size_t col = (size_t)blockIdx.x * 128 + wc + n * 16 + l15;
      #pragma unroll
      for (int j = 0; j < 4; ++j) {
        size_t row = (size_t)blockIdx.y * 128 + wr + m * 16 + r4 + j;
        C[row * ldC + col] = f2bf(acc[m][n][j]);
      }
    }
}

// ---------- row helpers ----------
__device__ __forceinline__ void load_bf16_row(const u16* p, int lane, float v[16]) {
  #pragma unroll
  for (int j = 0; j < 4; ++j) {
    int idx = j * 64 + lane;
    ushort4 a = ((const ushort4*)p)[idx];
    v[4*j+0] = bf2f(a.x); v[4*j+1] = bf2f(a.y); v[4*j+2] = bf2f(a.z); v[4*j+3] = bf2f(a.w);
  }
}
__device__ __forceinline__ void load_f32_row(const float* p, int lane, float v[16]) {
  #pragma unroll
  for (int j = 0; j < 4; ++j) {
    int idx = j * 64 + lane;
    float4 a = ((const float4*)p)[idx];
    v[4*j+0] = a.x; v[4*j+1] = a.y; v[4*j+2] = a.z; v[4*j+3] = a.w;
  }
}

struct RowCtx {
  float scale_h, hnc, ath, scale_x, xn, atx;
};

__device__ __forceinline__ RowCtx make_ctx(float n_h, float n_x) {
  RowCtx c;
  c.scale_h = (n_h > 0.9999f) ? 0.9999f * frcp(n_h + 1e-10f) : 1.0f;
  float hn = n_h * c.scale_h;
  c.hnc = fmaxf(hn, 1e-10f);
  c.ath = fatanh(hn);
  float nxc = fmaxf(n_x, 1e-10f);
  c.scale_x = ftanh(nxc) * frcp(nxc);
  c.xn = fmaxf(n_x * c.scale_x, 1e-10f);
  c.atx = fatanh(c.xn);
  return c;
}

// one_transform + log0 + sigmoid for one gate (gh = state_raw@W, gx = inputs_raw@U)
__device__ __forceinline__ void gate_sig(const float gh[16], const float gx[16], const float bb[16],
                                         const RowCtx& c, float out[16], float sv[16]) {
  float sh = 0.f, sx = 0.f, dxy = 0.f;
  #pragma unroll
  for (int j = 0; j < 16; ++j) { sh += gh[j]*gh[j]; sx += gx[j]*gx[j]; dxy += gh[j]*gx[j]; }
  sh = wred(sh); sx = wred(sx); dxy = wred(dxy);
  float mhn = fmaxf(c.scale_h * sqrtf(sh), 1e-10f);
  float th  = ftanh(mhn * frcp(c.hnc) * c.ath);
  float ca  = th * c.scale_h * frcp(mhn);      // u[j] = ca*gh[j]
  float mxn = fmaxf(c.scale_x * sqrtf(sx), 1e-10f);
  float tx  = ftanh(mxn * frcp(c.xn) * c.atx);
  float cb  = tx * c.scale_x * frcp(mxn);      // v[j] = cb*gx[j]
  float uv = ca * cb * dxy;
  float u2 = th * th, v2 = tx * tx;
  float rden = frcp(1.f + 2.f*uv + u2*v2 + 1e-10f);
  float c1 = (1.f + 2.f*uv + v2) * rden * ca;
  float c2 = (1.f - u2) * rden * cb;
  float uvb = 0.f, u2s = 0.f, v2b = 0.f;
  #pragma unroll
  for (int j = 0; j < 16; ++j) {
    sv[j] = c1 * gh[j] + c2 * gx[j];
    uvb += sv[j] * bb[j]; u2s += sv[j] * sv[j]; v2b += bb[j] * bb[j];
  }
  uvb = wred(uvb); u2s = wred(u2s); v2b = wred(v2b);
  float rden2 = frcp(1.f + 2.f*uvb + u2s*v2b + 1e-10f);
  float d1 = (1.f + 2.f*uvb + v2b) * rden2, d2 = (1.f - u2s) * rden2;
  float s3 = 0.f;
  #pragma unroll
  for (int j = 0; j < 16; ++j) { sv[j] = d1 * sv[j] + d2 * bb[j]; s3 += sv[j]*sv[j]; }
  s3 = wred(s3);
  float ns = sqrtf(s3);
  float ps = (ns > 0.99999f) ? 0.99999f * frcp(ns + 1e-10f) : 1.0f;
  float nres = fmaxf(ns * ps, 1e-10f);
  float g = fatanh(nres) * frcp(nres) * ps;
  #pragma unroll
  for (int j = 0; j < 16; ++j) out[j] = fsig(g * sv[j]);
}

// ---------- gates: z (bf16 -> G01 cols 1024..2047), r, r_point_h (bf16 -> hbuf), rn ----------
__global__ __launch_bounds__(256) void gates_k(
    u16* G01, const u16* __restrict__ G23,
    u16* hbuf,                        // in: state bf16; out: r_point_h bf16
    const float* __restrict__ bz, const float* __restrict__ br,
    const float* __restrict__ nxA, const float* __restrict__ nhA,
    float* __restrict__ rnA, int B) {
  int row = blockIdx.x * 4 + (threadIdx.x >> 6);
  if (row >= B) return;
  int lane = threadIdx.x & 63;
  size_t base  = (size_t)row * DHID;       // hbuf rows (stride 1024)
  size_t base2 = (size_t)row * 2048;       // G01/G23 rows (stride 2048)
  RowCtx c = make_ctx(nhA[row], nxA[row]);

  float gh[16], gx[16], bb[16], st[16], out[16], sv[16];
  load_bf16_row(hbuf + base, lane, st);    // bf16 state (rph is bf16-quantized anyway)

  // z gate
  load_bf16_row(G01 + base2, lane, gh);          // state@Wz
  load_bf16_row(G23 + base2, lane, gx);          // inputs@Uz
  load_f32_row(bz, lane, bb);
  gate_sig(gh, gx, bb, c, out, sv);
  float zo[16];
  #pragma unroll
  for (int j = 0; j < 16; ++j) zo[j] = out[j];

  // r gate
  load_bf16_row(G01 + base2 + DHID, lane, gh);   // state@Wr
  load_bf16_row(G23 + base2 + DHID, lane, gx);   // inputs@Ur
  load_f32_row(br, lane, bb);
  gate_sig(gh, gx, bb, c, out, sv);

  // z -> bf16 into G01 cols 1024..2047 (r-products consumed above)
  #pragma unroll
  for (int j = 0; j < 4; ++j) {
    int idx = j * 64 + lane;
    ((ushort4*)(G01 + base2 + DHID))[idx] = make_ushort4(
        f2bf(zo[4*j+0]), f2bf(zo[4*j+1]), f2bf(zo[4*j+2]), f2bf(zo[4*j+3]));
  }

  // r_point_h = project(mob_pw(state_proj, r), 1e-4)
  float mxv[16]; float s = 0.f;
  #pragma unroll
  for (int j = 0; j < 16; ++j) { mxv[j] = st[j] * c.scale_h * out[j]; s += mxv[j]*mxv[j]; }
  s = wred(s);
  float mxn = fmaxf(sqrtf(s), 1e-10f);
  float t = ftanh(mxn * frcp(c.hnc) * c.ath);
  float cc = t * frcp(mxn);
  float nrp = t;
  float psc = (nrp > 0.9999f) ? 0.9999f * frcp(nrp + 1e-10f) : 1.0f;
  cc *= psc; nrp *= psc;
  #pragma unroll
  for (int j = 0; j < 4; ++j) {
    int idx = j * 64 + lane;
    ((ushort4*)(hbuf + base))[idx] = make_ushort4(
        f2bf(cc*mxv[4*j+0]), f2bf(cc*mxv[4*j+1]), f2bf(cc*mxv[4*j+2]), f2bf(cc*mxv[4*j+3]));
  }
  if (lane == 0) rnA[row] = nrp;
}

// ---------- final: h_tilde, update, new_h ----------
__global__ __launch_bounds__(256) void final_k(
    const u16* __restrict__ G01, const u16* __restrict__ G23,
    const float* __restrict__ state, const float* __restrict__ bh,
    const float* __restrict__ nxA, const float* __restrict__ nhA, const float* __restrict__ rnA,
    float* __restrict__ out, int B) {
  int row = blockIdx.x * 4 + (threadIdx.x >> 6);
  if (row >= B) return;
  int lane = threadIdx.x & 63;
  size_t base  = (size_t)row * DHID;
  size_t base2 = (size_t)row * 2048;
  float n_h = nhA[row], n_x = nxA[row], rn = rnA[row];
  float scale_h = (n_h > 0.9999f) ? 0.9999f * frcp(n_h + 1e-10f) : 1.0f;
  float hn = n_h * scale_h;
  float nxc = fmaxf(n_x, 1e-10f);
  float scale_x = ftanh(nxc) * frcp(nxc);
  float xn = fmaxf(n_x * scale_x, 1e-10f);
  float atx = fatanh(xn);
  float hna = fmaxf(rn, 1e-10f);
  float atr = fatanh(rn);

  float gh[16], gx[16], bb[16], st[16], zz[16], sv[16];
  load_f32_row(state + base, lane, st);
  load_bf16_row(G01 + base2 + DHID, lane, zz);  // z (bf16) from gates_k
  load_bf16_row(G01 + base2, lane, gh);          // r_point_h@Wh
  load_bf16_row(G23 + base2, lane, gx);          // inputs@Uh
  load_f32_row(bh, lane, bb);

  // a = mob_matmul(r_point_h, Wh); b = mob_matmul(hyp_x, Uh)
  float sh = 0.f, sx = 0.f, dxy = 0.f;
  #pragma unroll
  for (int j = 0; j < 16; ++j) { sh += gh[j]*gh[j]; sx += gx[j]*gx[j]; dxy += gh[j]*gx[j]; }
  sh = wred(sh); sx = wred(sx); dxy = wred(dxy);
  float mhn = fmaxf(sqrtf(sh), 1e-10f);
  float ta = ftanh(mhn * frcp(hna) * atr);
  float ca = ta * frcp(mhn);
  float mxn = fmaxf(scale_x * sqrtf(sx), 1e-10f);
  float tb = ftanh(mxn * frcp(xn) * atx);
  float cb = tb * scale_x * frcp(mxn);
  float uv = ca * cb * dxy;
  float u2 = ta * ta, v2 = tb * tb;
  float rden = frcp(1.f + 2.f*uv + u2*v2 + 1e-10f);
  float c1 = (1.f + 2.f*uv + v2) * rden * ca;
  float c2 = (1.f - u2) * rden * cb;
  float uvb = 0.f, u2s = 0.f, v2b = 0.f;
  #pragma unroll
  for (int j = 0; j < 16; ++j) {
    sv[j] = c1 * gh[j] + c2 * gx[j];
    uvb += sv[j]*bb[j]; u2s += sv[j]*sv[j]; v2b += bb[j]*bb[j];
  }
  uvb = wred(uvb); u2s = wred(u2s); v2b = wred(v2b);
  float rden2 = frcp(1.f + 2.f*uvb + u2s*v2b + 1e-10f);
  float d1 = (1.f + 2.f*uvb + v2b) * rden2, d2 = (1.f - u2s) * rden2;
  float s3 = 0.f;
  #pragma unroll
  for (int j = 0; j < 16; ++j) { sv[j] = d1 * sv[j] + d2 * bb[j]; s3 += sv[j]*sv[j]; }
  s3 = wred(s3);
  float ns = sqrtf(s3);
  float p1 = (ns > 0.99999f) ? 0.99999f * frcp(ns + 1e-10f) : 1.0f;
  float n1 = ns * p1;
  float p2 = (n1 > 0.9999f) ? 0.9999f * frcp(n1 + 1e-10f) : 1.0f;
  float pc = p1 * p2;
  float nht = n1 * p2;
  #pragma unroll
  for (int j = 0; j < 16; ++j) sv[j] *= pc;   // sv = h_tilde

  // m = mob_add(-state_proj, h_tilde)
  float dv = 0.f;
  #pragma unroll
  for (int j = 0; j < 16; ++j) dv += st[j] * sv[j];
  dv = wred(dv);
  float uv2 = -scale_h * dv;
  float u2m = hn * hn, v2m = nht * nht;
  float rden3 = frcp(1.f + 2.f*uv2 + u2m*v2m + 1e-10f);
  float e1 = -(1.f + 2.f*uv2 + v2m) * rden3 * scale_h;  // * st
  float e2 = (1.f - u2m) * rden3;                       // * sv
  float mv[16]; float sm = 0.f;
  #pragma unroll
  for (int j = 0; j < 16; ++j) { mv[j] = e1*st[j] + e2*sv[j]; sm += mv[j]*mv[j]; }
  sm = wred(sm);
  float vn = fmaxf(sqrtf(sm), 1e-10f);
  float atv = fatanh(vn);
  // update = mob_pw(m, z)
  float mx2[16]; float s4 = 0.f;
  #pragma unroll
  for (int j = 0; j < 16; ++j) { mx2[j] = mv[j]*zz[j]; s4 += mx2[j]*mx2[j]; }
  s4 = wred(s4);
  float mxn2 = fmaxf(sqrtf(s4), 1e-10f);
  float tu = ftanh(mxn2 * frcp(vn) * atv);
  float cu2 = tu * frcp(mxn2);                          // upd = cu2*mx2
  // new_h = project(mob_add(state_proj, upd), 1e-5)
  float d5 = 0.f;
  #pragma unroll
  for (int j = 0; j < 16; ++j) d5 += st[j]*mx2[j];
  d5 = wred(d5);
  float uv3 = scale_h * cu2 * d5;
  float u2f = hn * hn, v2f = tu * tu;
  float rden4 = frcp(1.f + 2.f*uv3 + u2f*v2f + 1e-10f);
  float f1 = (1.f + 2.f*uv3 + v2f) * rden4 * scale_h;   // * st
  float f2 = (1.f - u2f) * rden4 * cu2;                 // * mx2
  float nh4[16]; float s5 = 0.f;
  #pragma unroll
  for (int j = 0; j < 16; ++j) { nh4[j] = f1*st[j] + f2*mx2[j]; s5 += nh4[j]*nh4[j]; }
  s5 = wred(s5);
  float nf = sqrtf(s5);
  float pf = (nf > 0.99999f) ? 0.99999f * frcp(nf + 1e-10f) : 1.0f;
  #pragma unroll
  for (int j = 0; j < 4; ++j) {
    int idx = j * 64 + lane;
    ((float4*)(out + base))[idx] = make_float4(pf*nh4[4*j], pf*nh4[4*j+1], pf*nh4[4*j+2], pf*nh4[4*j+3]);
  }
}

extern "C" void kernel_launch(void* const* d_in, const int* in_sizes, int n_in,
                              void* d_out, int out_size, void* d_ws, size_t ws_size,
                              hipStream_t stream) {
  const float* inputs = (const float*)d_in[0];
  const float* state  = (const float*)d_in[1];
  const float* Wz = (const float*)d_in[2];
  const float* Uz = (const float*)d_in[3];
  const float* bz = (const float*)d_in[4];
  const float* Wr = (const float*)d_in[5];
  const float* Ur = (const float*)d_in[6];
  const float* br = (const float*)d_in[7];
  const float* Wh = (const float*)d_in[8];
  const float* Uh = (const float*)d_in[9];
  const float* bh = (const float*)d_in[10];
  const int B = in_sizes[0] / DHID;
  const size_t MD = (size_t)B * DHID;
  const size_t WD = (size_t)DHID * DHID;

  char* p = (char*)d_ws;
  u16* xb   = (u16*)p; p += MD * 2;
  u16* hb   = (u16*)p; p += MD * 2;        // state bf16, later r_point_h bf16
  u16* Wt01 = (u16*)p; p += WD * 2 * 2;    // [Wz^T ; Wr^T]  (2048 x 1024)
  u16* Wt34 = (u16*)p; p += WD * 2 * 2;    // [Uz^T ; Ur^T]
  u16* Wt2  = (u16*)p; p += WD * 2;        // Wh^T
  u16* Wt5  = (u16*)p; p += WD * 2;        // Uh^T
  u16* G01  = (u16*)p; p += MD * 2 * 2;    // B x 2048
  u16* G23  = (u16*)p; p += MD * 2 * 2;    // B x 2048
  float* nx = (float*)p; p += (size_t)B * 4;
  float* nh = (float*)p; p += (size_t)B * 4;
  float* rn = (float*)p; p += (size_t)B * 4;
  if ((size_t)(p - (char*)d_ws) > ws_size) return;

  prep<<<B/4, 256, 0, stream>>>(inputs, state, xb, hb, nx, nh, B);

  W6 wp;
  wp.s[0] = Wz; wp.s[1] = Wr; wp.s[2] = Uz; wp.s[3] = Ur; wp.s[4] = Wh; wp.s[5] = Uh;
  wp.d[0] = Wt01; wp.d[1] = Wt01 + WD; wp.d[2] = Wt34; wp.d[3] = Wt34 + WD;
  wp.d[4] = Wt2;  wp.d[5] = Wt5;
  dim3 tb(32, 8), tg(DHID/32, DHID/32, 6);
  wconv_all<<<tg, tb, 0, stream>>>(wp);

  // stage 1: two fused N=2048 GEMMs (A shared per pair), batched z=2
  GB g1;
  g1.A[0] = hb; g1.Bt[0] = Wt01; g1.C[0] = G01;   // state  @ [Wz|Wr]
  g1.A[1] = xb; g1.Bt[1] = Wt34; g1.C[1] = G23;   // inputs @ [Uz|Ur]
  dim3 gg1(2*DHID/128, B/128, 2);   // x = N-dim fastest -> A-panel reuse
  gemm_bf16<<<gg1, 256, 0, stream>>>(g1, DHID, 2*DHID);

  gates_k<<<B/4, 256, 0, stream>>>(G01, G23, hb, bz, br, nx, nh, rn, B);

  // stage 2: 2 GEMMs (N=1024), outputs strided into G01/G23 cols 0..1023
  GB g2;
  g2.A[0] = hb; g2.Bt[0] = Wt2; g2.C[0] = G01;    // r_point_h @ Wh
  g2.A[1] = xb; g2.Bt[1] = Wt5; g2.C[1] = G23;    // inputs    @ Uh
  dim3 gg2(DHID/128, B/128, 2);
  gemm_bf16<<<gg2, 256, 0, stream>>>(g2, DHID, 2*DHID);

  final_k<<<B/4, 256, 0, stream>>>(G01, G23, state, bh, nx, nh, rn, (float*)d_out, B);
}

// Round 7
// 378.747 us; speedup vs baseline: 1.2898x; 1.0097x over previous
//
#include <hip/hip_runtime.h>
#include <math.h>

typedef unsigned short u16;
typedef __attribute__((ext_vector_type(8))) short bf16x8;
typedef __attribute__((ext_vector_type(4))) float f32x4;

#define DHID 1024

__device__ __forceinline__ u16 f2bf(float f) {
  union { float f; unsigned u; } v; v.f = f;
  unsigned u = v.u;
  u = (u + 0x7fffu + ((u >> 16) & 1u)) >> 16;
  return (u16)u;
}
__device__ __forceinline__ float bf2f(u16 h) {
  union { unsigned u; float f; } v; v.u = ((unsigned)h) << 16;
  return v.f;
}
__device__ __forceinline__ float wred(float v) {
  #pragma unroll
  for (int m = 32; m > 0; m >>= 1) v += __shfl_xor(v, m, 64);
  return v;
}
// ---- fast math: v_rcp_f32 / v_exp_f32 / v_log_f32 based ----
__device__ __forceinline__ float frcp(float x) { return __builtin_amdgcn_rcpf(x); }
__device__ __forceinline__ float ftanh(float x) {
  x = fminf(fmaxf(x, -15.f), 15.f);            // tanh(15) = 1 - 1e-13; avoids inf*0
  float t = __expf(2.f * x);
  return (t - 1.f) * frcp(t + 1.f);
}
__device__ __forceinline__ float fatanh(float x) {   // includes EPS clamp of reference
  x = fminf(fmaxf(x, -1.0f + 1e-5f), 1.0f - 1e-5f);
  return 0.5f * __logf((1.f + x) * frcp(1.f - x));
}
__device__ __forceinline__ float fsig(float x) {     // 1/(1+e^-x)
  return frcp(1.f + __expf(-x));
}

// ---------- fused weight convert+transpose for all 6: dst[n][k] = bf16(src[k][n]) ----------
struct W6 { const float* s[6]; u16* d[6]; };
__global__ __launch_bounds__(256) void wconv_all(W6 p) {
  const float* __restrict__ src = p.s[blockIdx.z];
  u16* __restrict__ dst = p.d[blockIdx.z];
  __shared__ float t[32][33];
  int bx = blockIdx.x * 32, by = blockIdx.y * 32;
  int tx = threadIdx.x, ty = threadIdx.y;
  #pragma unroll
  for (int r = 0; r < 32; r += 8)
    t[ty + r][tx] = src[(size_t)(by + ty + r) * DHID + bx + tx];
  __syncthreads();
  #pragma unroll
  for (int r = 0; r < 32; r += 8)
    dst[(size_t)(bx + ty + r) * DHID + by + tx] = f2bf(t[tx][ty + r]);
}

// ---------- prep: row norms + bf16 casts ----------
__global__ __launch_bounds__(256) void prep(const float* __restrict__ x, const float* __restrict__ h,
    u16* __restrict__ xb, u16* __restrict__ hb, float* __restrict__ nx, float* __restrict__ nh, int B) {
  int row = blockIdx.x * 4 + (threadIdx.x >> 6);
  if (row >= B) return;
  int lane = threadIdx.x & 63;
  size_t base = (size_t)row * DHID;
  const float4* xr = (const float4*)(x + base);
  const float4* hr = (const float4*)(h + base);
  ushort4* xo = (ushort4*)(xb + base);
  ushort4* ho = (ushort4*)(hb + base);
  float sx = 0.f, sh = 0.f;
  #pragma unroll
  for (int j = 0; j < 4; ++j) {
    int idx = j * 64 + lane;
    float4 a = xr[idx], b = hr[idx];
    sx += a.x*a.x + a.y*a.y + a.z*a.z + a.w*a.w;
    sh += b.x*b.x + b.y*b.y + b.z*b.z + b.w*b.w;
    xo[idx] = make_ushort4(f2bf(a.x), f2bf(a.y), f2bf(a.z), f2bf(a.w));
    ho[idx] = make_ushort4(f2bf(b.x), f2bf(b.y), f2bf(b.z), f2bf(b.w));
  }
  sx = wred(sx); sh = wred(sh);
  if (lane == 0) { nx[row] = sqrtf(sx); nh[row] = sqrtf(sh); }
}

// ---------- async global->LDS staging helper (width 16B) ----------
__device__ __forceinline__ void gll16(const void* g, void* l) {
  __builtin_amdgcn_global_load_lds((const __attribute__((address_space(1))) unsigned int*)g,
                                   (__attribute__((address_space(3))) unsigned int*)l, 16, 0, 0);
}

// ---------- batched bf16 MFMA GEMM: C[.][ldC] col-block x, row-block y ----------
// C[row][col] = sum_k A[row][k] * Bt[col][k]. grid.x = N/128, grid.y = M/128, grid.z = batch.
// LDS stored layout XOR-swizzled via pre-swizzled GLOBAL source col (m173 pattern);
// reads apply same XOR -> 0 bank conflicts (round-5/6 PMC: SQ_LDS_BANK_CONFLICT = 0).
struct GB { const u16* A[2]; const u16* Bt[2]; u16* C[2]; };
__global__ __launch_bounds__(256) void gemm_bf16(GB gb, int K, int ldC) {
  const u16* __restrict__ A  = gb.A[blockIdx.z];
  const u16* __restrict__ Bt = gb.Bt[blockIdx.z];
  u16* __restrict__ C        = gb.C[blockIdx.z];
  __shared__ __align__(16) u16 As[128 * 64];
  __shared__ __align__(16) u16 Bs[128 * 64];
  const int tid = threadIdx.x;
  const int lane = tid & 63;
  const int wid = tid >> 6;
  const int wr = (wid >> 1) * 64;
  const int wc = (wid & 1) * 64;
  const int l15 = lane & 15;
  const int koff = (lane >> 4) * 8;
  const int cswz = (l15 & 7) << 3;            // read-side XOR (u16 units)
  const int srow = lane >> 3;                  // 0..7 within 8-row chunk
  const int scol = ((lane & 7) ^ srow) * 8;    // pre-swizzled global u16 col
  const size_t abase = (size_t)(blockIdx.y * 128) * K;
  const size_t bbase = (size_t)(blockIdx.x * 128) * K;
  f32x4 acc[4][4] = {};
  for (int k0 = 0; k0 < K; k0 += 64) {
    __syncthreads();   // previous tile fully consumed
    #pragma unroll
    for (int i = 0; i < 4; ++i) {
      int rb = (i * 4 + wid) * 8;
      gll16(A  + abase + (size_t)(rb + srow) * K + k0 + scol, &As[rb * 64]);
      gll16(Bt + bbase + (size_t)(rb + srow) * K + k0 + scol, &Bs[rb * 64]);
    }
    __syncthreads();   // compiler drains vmcnt(0) before barrier
    #pragma unroll
    for (int ks = 0; ks < 64; ks += 32) {
      bf16x8 af[4], bg[4];
      #pragma unroll
      for (int m = 0; m < 4; ++m)
        af[m] = *(const bf16x8*)&As[(wr + m*16 + l15) * 64 + ((ks + koff) ^ cswz)];
      #pragma unroll
      for (int n = 0; n < 4; ++n)
        bg[n] = *(const bf16x8*)&Bs[(wc + n*16 + l15) * 64 + ((ks + koff) ^ cswz)];
      #pragma unroll
      for (int m = 0; m < 4; ++m)
        #pragma unroll
        for (int n = 0; n < 4; ++n)
          acc[m][n] = __builtin_amdgcn_mfma_f32_16x16x32_bf16(af[m], bg[n], acc[m][n], 0, 0, 0);
    }
  }
  const int r4 = (lane >> 4) * 4;
  #pragma unroll
  for (int m = 0; m < 4; ++m)
    #pragma unroll
    for (int n = 0; n < 4; ++n) {
      size_t col = (size_t)blockIdx.x * 128 + wc + n * 16 + l15;
      #pragma unroll
      for (int j = 0; j < 4; ++j) {
        size_t row = (size_t)blockIdx.y * 128 + wr + m * 16 + r4 + j;
        C[row * ldC + col] = f2bf(acc[m][n][j]);
      }
    }
}

// ---------- row helpers ----------
__device__ __forceinline__ void load_bf16_row(const u16* p, int lane, float v[16]) {
  #pragma unroll
  for (int j = 0; j < 4; ++j) {
    int idx = j * 64 + lane;
    ushort4 a = ((const ushort4*)p)[idx];
    v[4*j+0] = bf2f(a.x); v[4*j+1] = bf2f(a.y); v[4*j+2] = bf2f(a.z); v[4*j+3] = bf2f(a.w);
  }
}
__device__ __forceinline__ void load_f32_row(const float* p, int lane, float v[16]) {
  #pragma unroll
  for (int j = 0; j < 4; ++j) {
    int idx = j * 64 + lane;
    float4 a = ((const float4*)p)[idx];
    v[4*j+0] = a.x; v[4*j+1] = a.y; v[4*j+2] = a.z; v[4*j+3] = a.w;
  }
}

struct RowCtx {
  float scale_h, hnc, ath, scale_x, xn, atx;
};

__device__ __forceinline__ RowCtx make_ctx(float n_h, float n_x) {
  RowCtx c;
  c.scale_h = (n_h > 0.9999f) ? 0.9999f * frcp(n_h + 1e-10f) : 1.0f;
  float hn = n_h * c.scale_h;
  c.hnc = fmaxf(hn, 1e-10f);
  c.ath = fatanh(hn);
  float nxc = fmaxf(n_x, 1e-10f);
  c.scale_x = ftanh(nxc) * frcp(nxc);
  c.xn = fmaxf(n_x * c.scale_x, 1e-10f);
  c.atx = fatanh(c.xn);
  return c;
}

// one_transform + log0 + sigmoid for one gate (gh = state_raw@W, gx = inputs_raw@U)
__device__ __forceinline__ void gate_sig(const float gh[16], const float gx[16], const float bb[16],
                                         const RowCtx& c, float out[16], float sv[16]) {
  float sh = 0.f, sx = 0.f, dxy = 0.f;
  #pragma unroll
  for (int j = 0; j < 16; ++j) { sh += gh[j]*gh[j]; sx += gx[j]*gx[j]; dxy += gh[j]*gx[j]; }
  sh = wred(sh); sx = wred(sx); dxy = wred(dxy);
  float mhn = fmaxf(c.scale_h * sqrtf(sh), 1e-10f);
  float th  = ftanh(mhn * frcp(c.hnc) * c.ath);
  float ca  = th * c.scale_h * frcp(mhn);      // u[j] = ca*gh[j]
  float mxn = fmaxf(c.scale_x * sqrtf(sx), 1e-10f);
  float tx  = ftanh(mxn * frcp(c.xn) * c.atx);
  float cb  = tx * c.scale_x * frcp(mxn);      // v[j] = cb*gx[j]
  float uv = ca * cb * dxy;
  float u2 = th * th, v2 = tx * tx;
  float rden = frcp(1.f + 2.f*uv + u2*v2 + 1e-10f);
  float c1 = (1.f + 2.f*uv + v2) * rden * ca;
  float c2 = (1.f - u2) * rden * cb;
  float uvb = 0.f, u2s = 0.f, v2b = 0.f;
  #pragma unroll
  for (int j = 0; j < 16; ++j) {
    sv[j] = c1 * gh[j] + c2 * gx[j];
    uvb += sv[j] * bb[j]; u2s += sv[j] * sv[j]; v2b += bb[j] * bb[j];
  }
  uvb = wred(uvb); u2s = wred(u2s); v2b = wred(v2b);
  float rden2 = frcp(1.f + 2.f*uvb + u2s*v2b + 1e-10f);
  float d1 = (1.f + 2.f*uvb + v2b) * rden2, d2 = (1.f - u2s) * rden2;
  float s3 = 0.f;
  #pragma unroll
  for (int j = 0; j < 16; ++j) { sv[j] = d1 * sv[j] + d2 * bb[j]; s3 += sv[j]*sv[j]; }
  s3 = wred(s3);
  float ns = sqrtf(s3);
  float ps = (ns > 0.99999f) ? 0.99999f * frcp(ns + 1e-10f) : 1.0f;
  float nres = fmaxf(ns * ps, 1e-10f);
  float g = fatanh(nres) * frcp(nres) * ps;
  #pragma unroll
  for (int j = 0; j < 16; ++j) out[j] = fsig(g * sv[j]);
}

// ---------- gates_r: r gate only -> r_point_h (bf16 -> hbuf), rn ----------
__global__ __launch_bounds__(256) void gates_r(
    const u16* __restrict__ G01, const u16* __restrict__ G23,
    u16* hbuf,                        // in: state bf16; out: r_point_h bf16
    const float* __restrict__ br,
    const float* __restrict__ nxA, const float* __restrict__ nhA,
    float* __restrict__ rnA, int B) {
  int row = blockIdx.x * 4 + (threadIdx.x >> 6);
  if (row >= B) return;
  int lane = threadIdx.x & 63;
  size_t base  = (size_t)row * DHID;       // hbuf rows (stride 1024)
  size_t base2 = (size_t)row * 2048;       // G01/G23 rows (stride 2048)
  RowCtx c = make_ctx(nhA[row], nxA[row]);

  float gh[16], gx[16], bb[16], st[16], out[16], sv[16];
  load_bf16_row(hbuf + base, lane, st);          // bf16 state
  load_bf16_row(G01 + base2 + DHID, lane, gh);   // state@Wr
  load_bf16_row(G23 + base2 + DHID, lane, gx);   // inputs@Ur
  load_f32_row(br, lane, bb);
  gate_sig(gh, gx, bb, c, out, sv);

  // r_point_h = project(mob_pw(state_proj, r), 1e-4)
  float mxv[16]; float s = 0.f;
  #pragma unroll
  for (int j = 0; j < 16; ++j) { mxv[j] = st[j] * c.scale_h * out[j]; s += mxv[j]*mxv[j]; }
  s = wred(s);
  float mxn = fmaxf(sqrtf(s), 1e-10f);
  float t = ftanh(mxn * frcp(c.hnc) * c.ath);
  float cc = t * frcp(mxn);
  float nrp = t;
  float psc = (nrp > 0.9999f) ? 0.9999f * frcp(nrp + 1e-10f) : 1.0f;
  cc *= psc; nrp *= psc;
  #pragma unroll
  for (int j = 0; j < 4; ++j) {
    int idx = j * 64 + lane;
    ((ushort4*)(hbuf + base))[idx] = make_ushort4(
        f2bf(cc*mxv[4*j+0]), f2bf(cc*mxv[4*j+1]), f2bf(cc*mxv[4*j+2]), f2bf(cc*mxv[4*j+3]));
  }
  if (lane == 0) rnA[row] = nrp;
}

// ---------- final: z gate (from G cols 0..1023), h_tilde, update, new_h ----------
__global__ __launch_bounds__(256) void final_k(
    const u16* __restrict__ G01, const u16* __restrict__ G23,
    const float* __restrict__ state,
    const float* __restrict__ bz, const float* __restrict__ bh,
    const float* __restrict__ nxA, const float* __restrict__ nhA, const float* __restrict__ rnA,
    float* __restrict__ out, int B) {
  int row = blockIdx.x * 4 + (threadIdx.x >> 6);
  if (row >= B) return;
  int lane = threadIdx.x & 63;
  size_t base  = (size_t)row * DHID;
  size_t base2 = (size_t)row * 2048;
  float n_h = nhA[row], n_x = nxA[row], rn = rnA[row];
  RowCtx c = make_ctx(n_h, n_x);
  float scale_h = c.scale_h;
  float hn = n_h * scale_h;
  float scale_x = c.scale_x;
  float xn = c.xn;
  float atx = c.atx;
  float hna = fmaxf(rn, 1e-10f);
  float atr = fatanh(rn);

  float gh[16], gx[16], bb[16], st[16], zz[16], sv[16];

  // ---- z gate (moved here from gates kernel; z never materialized) ----
  load_bf16_row(G01 + base2, lane, gh);          // state@Wz
  load_bf16_row(G23 + base2, lane, gx);          // inputs@Uz
  load_f32_row(bz, lane, bb);
  gate_sig(gh, gx, bb, c, zz, sv);

  // ---- h_tilde inputs ----
  load_f32_row(state + base, lane, st);
  load_bf16_row(G01 + base2 + DHID, lane, gh);   // r_point_h@Wh (stage-2 output)
  load_bf16_row(G23 + base2 + DHID, lane, gx);   // inputs@Uh    (stage-2 output)
  load_f32_row(bh, lane, bb);

  // a = mob_matmul(r_point_h, Wh); b = mob_matmul(hyp_x, Uh)
  float sh = 0.f, sx = 0.f, dxy = 0.f;
  #pragma unroll
  for (int j = 0; j < 16; ++j) { sh += gh[j]*gh[j]; sx += gx[j]*gx[j]; dxy += gh[j]*gx[j]; }
  sh = wred(sh); sx = wred(sx); dxy = wred(dxy);
  float mhn = fmaxf(sqrtf(sh), 1e-10f);
  float ta = ftanh(mhn * frcp(hna) * atr);
  float ca = ta * frcp(mhn);
  float mxn = fmaxf(scale_x * sqrtf(sx), 1e-10f);
  float tb = ftanh(mxn * frcp(xn) * atx);
  float cb = tb * scale_x * frcp(mxn);
  float uv = ca * cb * dxy;
  float u2 = ta * ta, v2 = tb * tb;
  float rden = frcp(1.f + 2.f*uv + u2*v2 + 1e-10f);
  float c1 = (1.f + 2.f*uv + v2) * rden * ca;
  float c2 = (1.f - u2) * rden * cb;
  float uvb = 0.f, u2s = 0.f, v2b = 0.f;
  #pragma unroll
  for (int j = 0; j < 16; ++j) {
    sv[j] = c1 * gh[j] + c2 * gx[j];
    uvb += sv[j]*bb[j]; u2s += sv[j]*sv[j]; v2b += bb[j]*bb[j];
  }
  uvb = wred(uvb); u2s = wred(u2s); v2b = wred(v2b);
  float rden2 = frcp(1.f + 2.f*uvb + u2s*v2b + 1e-10f);
  float d1 = (1.f + 2.f*uvb + v2b) * rden2, d2 = (1.f - u2s) * rden2;
  float s3 = 0.f;
  #pragma unroll
  for (int j = 0; j < 16; ++j) { sv[j] = d1 * sv[j] + d2 * bb[j]; s3 += sv[j]*sv[j]; }
  s3 = wred(s3);
  float ns = sqrtf(s3);
  float p1 = (ns > 0.99999f) ? 0.99999f * frcp(ns + 1e-10f) : 1.0f;
  float n1 = ns * p1;
  float p2 = (n1 > 0.9999f) ? 0.9999f * frcp(n1 + 1e-10f) : 1.0f;
  float pc = p1 * p2;
  float nht = n1 * p2;
  #pragma unroll
  for (int j = 0; j < 16; ++j) sv[j] *= pc;   // sv = h_tilde

  // m = mob_add(-state_proj, h_tilde)
  float dv = 0.f;
  #pragma unroll
  for (int j = 0; j < 16; ++j) dv += st[j] * sv[j];
  dv = wred(dv);
  float uv2 = -scale_h * dv;
  float u2m = hn * hn, v2m = nht * nht;
  float rden3 = frcp(1.f + 2.f*uv2 + u2m*v2m + 1e-10f);
  float e1 = -(1.f + 2.f*uv2 + v2m) * rden3 * scale_h;  // * st
  float e2 = (1.f - u2m) * rden3;                       // * sv
  float mv[16]; float sm = 0.f;
  #pragma unroll
  for (int j = 0; j < 16; ++j) { mv[j] = e1*st[j] + e2*sv[j]; sm += mv[j]*mv[j]; }
  sm = wred(sm);
  float vn = fmaxf(sqrtf(sm), 1e-10f);
  float atv = fatanh(vn);
  // update = mob_pw(m, z)
  float mx2[16]; float s4 = 0.f;
  #pragma unroll
  for (int j = 0; j < 16; ++j) { mx2[j] = mv[j]*zz[j]; s4 += mx2[j]*mx2[j]; }
  s4 = wred(s4);
  float mxn2 = fmaxf(sqrtf(s4), 1e-10f);
  float tu = ftanh(mxn2 * frcp(vn) * atv);
  float cu2 = tu * frcp(mxn2);                          // upd = cu2*mx2
  // new_h = project(mob_add(state_proj, upd), 1e-5)
  float d5 = 0.f;
  #pragma unroll
  for (int j = 0; j < 16; ++j) d5 += st[j]*mx2[j];
  d5 = wred(d5);
  float uv3 = scale_h * cu2 * d5;
  float u2f = hn * hn, v2f = tu * tu;
  float rden4 = frcp(1.f + 2.f*uv3 + u2f*v2f + 1e-10f);
  float f1 = (1.f + 2.f*uv3 + v2f) * rden4 * scale_h;   // * st
  float f2 = (1.f - u2f) * rden4 * cu2;                 // * mx2
  float nh4[16]; float s5 = 0.f;
  #pragma unroll
  for (int j = 0; j < 16; ++j) { nh4[j] = f1*st[j] + f2*mx2[j]; s5 += nh4[j]*nh4[j]; }
  s5 = wred(s5);
  float nf = sqrtf(s5);
  float pf = (nf > 0.99999f) ? 0.99999f * frcp(nf + 1e-10f) : 1.0f;
  #pragma unroll
  for (int j = 0; j < 4; ++j) {
    int idx = j * 64 + lane;
    ((float4*)(out + base))[idx] = make_float4(pf*nh4[4*j], pf*nh4[4*j+1], pf*nh4[4*j+2], pf*nh4[4*j+3]);
  }
}

extern "C" void kernel_launch(void* const* d_in, const int* in_sizes, int n_in,
                              void* d_out, int out_size, void* d_ws, size_t ws_size,
                              hipStream_t stream) {
  const float* inputs = (const float*)d_in[0];
  const float* state  = (const float*)d_in[1];
  const float* Wz = (const float*)d_in[2];
  const float* Uz = (const float*)d_in[3];
  const float* bz = (const float*)d_in[4];
  const float* Wr = (const float*)d_in[5];
  const float* Ur = (const float*)d_in[6];
  const float* br = (const float*)d_in[7];
  const float* Wh = (const float*)d_in[8];
  const float* Uh = (const float*)d_in[9];
  const float* bh = (const float*)d_in[10];
  const int B = in_sizes[0] / DHID;
  const size_t MD = (size_t)B * DHID;
  const size_t WD = (size_t)DHID * DHID;

  char* p = (char*)d_ws;
  u16* xb   = (u16*)p; p += MD * 2;
  u16* hb   = (u16*)p; p += MD * 2;        // state bf16, later r_point_h bf16
  u16* Wt01 = (u16*)p; p += WD * 2 * 2;    // [Wz^T ; Wr^T]  (2048 x 1024)
  u16* Wt34 = (u16*)p; p += WD * 2 * 2;    // [Uz^T ; Ur^T]
  u16* Wt2  = (u16*)p; p += WD * 2;        // Wh^T
  u16* Wt5  = (u16*)p; p += WD * 2;        // Uh^T
  u16* G01  = (u16*)p; p += MD * 2 * 2;    // B x 2048: [Wz·h | Wr·h -> rph@Wh]
  u16* G23  = (u16*)p; p += MD * 2 * 2;    // B x 2048: [Uz·x | Ur·x -> Uh·x]
  float* nx = (float*)p; p += (size_t)B * 4;
  float* nh = (float*)p; p += (size_t)B * 4;
  float* rn = (float*)p; p += (size_t)B * 4;
  if ((size_t)(p - (char*)d_ws) > ws_size) return;

  prep<<<B/4, 256, 0, stream>>>(inputs, state, xb, hb, nx, nh, B);

  W6 wp;
  wp.s[0] = Wz; wp.s[1] = Wr; wp.s[2] = Uz; wp.s[3] = Ur; wp.s[4] = Wh; wp.s[5] = Uh;
  wp.d[0] = Wt01; wp.d[1] = Wt01 + WD; wp.d[2] = Wt34; wp.d[3] = Wt34 + WD;
  wp.d[4] = Wt2;  wp.d[5] = Wt5;
  dim3 tb(32, 8), tg(DHID/32, DHID/32, 6);
  wconv_all<<<tg, tb, 0, stream>>>(wp);

  // stage 1: two fused N=2048 GEMMs (A shared per pair), batched z=2
  GB g1;
  g1.A[0] = hb; g1.Bt[0] = Wt01; g1.C[0] = G01;   // state  @ [Wz|Wr]
  g1.A[1] = xb; g1.Bt[1] = Wt34; g1.C[1] = G23;   // inputs @ [Uz|Ur]
  dim3 gg1(2*DHID/128, B/128, 2);
  gemm_bf16<<<gg1, 256, 0, stream>>>(g1, DHID, 2*DHID);

  // r gate only; rph (bf16) overwrites hb; cols 0..1023 of G01/G23 stay intact for final_k
  gates_r<<<B/4, 256, 0, stream>>>(G01, G23, hb, br, nx, nh, rn, B);

  // stage 2: 2 GEMMs (N=1024), outputs into the FREED r-slots (cols 1024..2047)
  GB g2;
  g2.A[0] = hb; g2.Bt[0] = Wt2; g2.C[0] = G01 + DHID;  // r_point_h @ Wh
  g2.A[1] = xb; g2.Bt[1] = Wt5; g2.C[1] = G23 + DHID;  // inputs    @ Uh
  dim3 gg2(DHID/128, B/128, 2);
  gemm_bf16<<<gg2, 256, 0, stream>>>(g2, DHID, 2*DHID);

  final_k<<<B/4, 256, 0, stream>>>(G01, G23, state, bz, bh, nx, nh, rn, (float*)d_out, B);
}